// Round 2
// baseline (632.611 us; speedup 1.0000x reference)
//
#include <hip/hip_runtime.h>
#include <hip/hip_bf16.h>

#define L_DIM 384
#define DPC 128
#define NH 4
#define DHD 32
#define HD 128
#define NROWS (L_DIM*L_DIM)

typedef __hip_bfloat16 bf16;
typedef __attribute__((ext_vector_type(8))) short bf8_t;   // 8 bf16 (4 VGPRs)
typedef __attribute__((ext_vector_type(4))) float f4_t;

__device__ __forceinline__ float bf2f(bf16 x){ return __bfloat162float(x); }
__device__ __forceinline__ bf16 f2bf(float x){ return __float2bfloat16(x); }

// ---------------------------------------------------------------------------
// Kernel 0: convert f32 weights to bf16 in workspace (5 matrices of 128x128).
__global__ __launch_bounds__(256) void k_prep(
    const float* __restrict__ Wq, const float* __restrict__ Wk, const float* __restrict__ Wv,
    const float* __restrict__ Wg, const float* __restrict__ Wo,
    bf16* __restrict__ Wqb, bf16* __restrict__ Wkb, bf16* __restrict__ Wvb,
    bf16* __restrict__ Wgb, bf16* __restrict__ Wob)
{
  const int idx = blockIdx.x * 256 + threadIdx.x;   // 64 blocks * 256 = 16384
  Wqb[idx] = f2bf(Wq[idx]);
  Wkb[idx] = f2bf(Wk[idx]);
  Wvb[idx] = f2bf(Wv[idx]);
  Wgb[idx] = f2bf(Wg[idx]);
  Wob[idx] = f2bf(Wo[idx]);
}

// ---------------------------------------------------------------------------
// Kernel 1b: LN(bias) + Wb projection -> bscore[h][i][j]  (f32, all-VALU)
// bias memory row t = (a*L + b) is bsrc[i=b, j=a]; wave per row.
__global__ __launch_bounds__(256) void k_bias_proj(
    const float* __restrict__ bias, const float* __restrict__ lng, const float* __restrict__ lnb,
    const float* __restrict__ Wb, float* __restrict__ bscore)
{
  const int tid = threadIdx.x;
  const int wave = tid >> 6, lane = tid & 63;
  const int t = blockIdx.x * 4 + wave;       // memory row of bias
  const int j = t / L_DIM, i = t % L_DIM;    // bsrc[i][j] = bias row t
  const int c = lane * 2;

  float g0 = lng[c], g1 = lng[c+1];
  float b0 = lnb[c], b1 = lnb[c+1];
  float w0[4], w1[4];
  #pragma unroll
  for (int h = 0; h < 4; ++h) { w0[h] = Wb[h*DPC + c]; w1[h] = Wb[h*DPC + c + 1]; }

  const float2 xv = *(const float2*)&bias[(size_t)t * DPC + c];
  float x0 = xv.x, x1 = xv.y;
  float s = x0 + x1, ss = x0*x0 + x1*x1;
  #pragma unroll
  for (int off = 32; off; off >>= 1) { s += __shfl_xor(s, off, 64); ss += __shfl_xor(ss, off, 64); }
  float mean = s * (1.f/128.f);
  float var  = ss * (1.f/128.f) - mean*mean;
  float rstd = rsqrtf(var + 1e-5f);
  float y0 = (x0-mean)*rstd*g0 + b0, y1 = (x1-mean)*rstd*g1 + b1;

  float p0 = y0*w0[0] + y1*w1[0], p1 = y0*w0[1] + y1*w1[1];
  float p2 = y0*w0[2] + y1*w1[2], p3 = y0*w0[3] + y1*w1[3];
  #pragma unroll
  for (int off = 32; off; off >>= 1) {
    p0 += __shfl_xor(p0, off, 64); p1 += __shfl_xor(p1, off, 64);
    p2 += __shfl_xor(p2, off, 64); p3 += __shfl_xor(p3, off, 64);
  }
  if (lane < 4) {
    float v = (lane==0) ? p0 : (lane==1) ? p1 : (lane==2) ? p2 : p3;
    bscore[((size_t)lane*L_DIM + i)*L_DIM + j] = v;
  }
}

// ---------------------------------------------------------------------------
// Kernel 1: LN(pair, transposed read, f32) + Q/K/V/G projections via bf16 MFMA.
// Block: 64 rows (fixed n, 64 consecutive i), 256 threads (4 waves).
__global__ __launch_bounds__(256) void k_pair_proj(
    const float* __restrict__ pair, const float* __restrict__ lng, const float* __restrict__ lnb,
    const bf16* __restrict__ Wq, const bf16* __restrict__ Wk, const bf16* __restrict__ Wv,
    const bf16* __restrict__ Wg, const float* __restrict__ bg,
    bf16* __restrict__ qo, bf16* __restrict__ ko, bf16* __restrict__ vT, bf16* __restrict__ gateo)
{
  __shared__ __align__(16) bf16 As[64][136];   // 136*2B = 272B = 17*16B: rows 16B-aligned
  __shared__ __align__(16) bf16 Cs[64][134];
  const int tid = threadIdx.x;
  const int wave = tid >> 6, lane = tid & 63;
  const int n = blockIdx.x / 6, i0 = (blockIdx.x % 6) * 64;
  const int m = lane & 15, q4 = lane >> 4;

  { // LayerNorm -> As (bf16)
    const int c = lane * 2;
    float g0 = lng[c], g1 = lng[c+1];
    float b0 = lnb[c], b1 = lnb[c+1];
    for (int r = wave*16; r < wave*16 + 16; ++r) {
      int i = i0 + r;
      const float2 xv = *(const float2*)&pair[((size_t)i*L_DIM + n)*DPC + c]; // p[n][i][:] = pair[i][n][:]
      float x0 = xv.x, x1 = xv.y;
      float s = x0 + x1, ss = x0*x0 + x1*x1;
      #pragma unroll
      for (int off = 32; off; off >>= 1) { s += __shfl_xor(s, off, 64); ss += __shfl_xor(ss, off, 64); }
      float mean = s * (1.f/128.f);
      float var  = ss * (1.f/128.f) - mean*mean;
      float rstd = rsqrtf(var + 1e-5f);
      As[r][c]   = f2bf((x0-mean)*rstd*g0 + b0);
      As[r][c+1] = f2bf((x1-mean)*rstd*g1 + b1);
    }
  }
  __syncthreads();

  bf8_t afr[4];
  #pragma unroll
  for (int ks = 0; ks < 4; ++ks)
    afr[ks] = *(const bf8_t*)&As[wave*16 + m][ks*32 + q4*8];

  const bf16* Ws[4] = {Wq, Wk, Wv, Wg};
  for (int sel = 0; sel < 4; ++sel) {
    const bf16* W = Ws[sel];
    #pragma unroll
    for (int nt = 0; nt < 8; ++nt) {
      f4_t acc = {0.f, 0.f, 0.f, 0.f};
      #pragma unroll
      for (int ks = 0; ks < 4; ++ks) {
        bf8_t bfr = *(const bf8_t*)&W[(size_t)(nt*16 + m)*DPC + ks*32 + q4*8];
        acc = __builtin_amdgcn_mfma_f32_16x16x32_bf16(afr[ks], bfr, acc, 0, 0, 0);
      }
      const int col = nt*16 + m;
      const float bgv = (sel == 3) ? bg[col] : 0.f;
      #pragma unroll
      for (int reg = 0; reg < 4; ++reg) {
        int row = wave*16 + q4*4 + reg;
        float v = acc[reg];
        if (sel == 3) v = 1.f / (1.f + __expf(-(v + bgv)));   // gate sigmoid
        Cs[row][col] = f2bf(v);
      }
    }
    __syncthreads();
    if (sel == 2) {
      // v transposed: vT[((n*4+h)*32+d)*L + j]  (j contiguous for PV B-frags)
      for (int u = tid; u < 4096; u += 256) {
        int colv = u >> 5, ii = (u & 31) * 2;
        int h = colv >> 5, d = colv & 31;
        size_t dst = ((size_t)(n*NH + h)*DHD + d)*L_DIM + i0 + ii;
        vT[dst]   = Cs[ii][colv];
        vT[dst+1] = Cs[ii+1][colv];
      }
    } else {
      bf16* dst = (sel == 0) ? qo : (sel == 1) ? ko : gateo;
      for (int u = tid; u < 4096; u += 256) {
        int r = u >> 6, c2 = (u & 63) * 2;
        size_t off = ((size_t)n*L_DIM + i0 + r)*HD + c2;
        dst[off]   = Cs[r][c2];
        dst[off+1] = Cs[r][c2+1];
      }
    }
    __syncthreads();
  }
}

// ---------------------------------------------------------------------------
// Kernel 2: S partials. Block = 128x128 tile of S[h], K-chunk = 48 n's (split-K=8).
__global__ __launch_bounds__(256) void k_qk(
    const bf16* __restrict__ qo, const bf16* __restrict__ ko, float* __restrict__ Spart)
{
  __shared__ __align__(16) bf16 As[128][56];   // 56*2B = 112B = 7*16B aligned
  __shared__ __align__(16) bf16 Bs[128][56];
  const int tid = threadIdx.x, wave = tid >> 6, lane = tid & 63;
  const int m = lane & 15, q4 = lane >> 4;
  const int b = blockIdx.x;
  const int ks = b / 36, rem = b % 36;
  const int h = rem / 9, t9 = rem % 9;
  const int i0 = (t9/3)*128, j0 = (t9%3)*128;
  const int wr = (wave >> 1)*64, wc = (wave & 1)*64;

  f4_t acc[4][4];
  #pragma unroll
  for (int a = 0; a < 4; ++a)
    #pragma unroll
    for (int c = 0; c < 4; ++c) acc[a][c] = (f4_t){0.f,0.f,0.f,0.f};

  for (int kt = 0; kt < 48; ++kt) {
    const int nIdx = ks*48 + kt;
    bf8_t ra[2], rb[2];
    #pragma unroll
    for (int u2 = 0; u2 < 2; ++u2) {
      int u = tid + u2*256;
      int row = u >> 2, seg = (u & 3) * 8;
      ra[u2] = *(const bf8_t*)&qo[((size_t)nIdx*L_DIM + i0 + row)*HD + h*DHD + seg];
      rb[u2] = *(const bf8_t*)&ko[((size_t)nIdx*L_DIM + j0 + row)*HD + h*DHD + seg];
    }
    __syncthreads();
    #pragma unroll
    for (int u2 = 0; u2 < 2; ++u2) {
      int u = tid + u2*256;
      int row = u >> 2, seg = (u & 3) * 8;
      *(bf8_t*)&As[row][seg] = ra[u2];
      *(bf8_t*)&Bs[row][seg] = rb[u2];
    }
    __syncthreads();
    bf8_t af[4], bfr[4];
    #pragma unroll
    for (int x = 0; x < 4; ++x) {
      af[x]  = *(const bf8_t*)&As[wr + x*16 + m][q4*8];
      bfr[x] = *(const bf8_t*)&Bs[wc + x*16 + m][q4*8];
    }
    #pragma unroll
    for (int mt = 0; mt < 4; ++mt)
      #pragma unroll
      for (int nt = 0; nt < 4; ++nt)
        acc[mt][nt] = __builtin_amdgcn_mfma_f32_16x16x32_bf16(af[mt], bfr[nt], acc[mt][nt], 0, 0, 0);
  }
  float* Sp = Spart + (size_t)(ks*NH + h)*L_DIM*L_DIM;
  #pragma unroll
  for (int mt = 0; mt < 4; ++mt)
    #pragma unroll
    for (int nt = 0; nt < 4; ++nt)
      #pragma unroll
      for (int reg = 0; reg < 4; ++reg) {
        int i = i0 + wr + mt*16 + q4*4 + reg;
        int j = j0 + wc + nt*16 + m;
        Sp[(size_t)i*L_DIM + j] = acc[mt][nt][reg];
      }
}

// ---------------------------------------------------------------------------
// Kernel 3: reduce split-K partials, scale, add bias score, softmax over j -> bf16 attn
__global__ __launch_bounds__(256) void k_softmax(
    const float* __restrict__ Spart, const float* __restrict__ bscore, bf16* __restrict__ attn)
{
  const int tid = threadIdx.x, wave = tid >> 6, lane = tid & 63;
  const int row = blockIdx.x*4 + wave;           // (h,i)
  const int h = row / L_DIM, i = row % L_DIM;
  const float sc = 0.17677669529663687f / 384.f; // SCALING * (1/L)
  float s[6]; float mx = -1e30f;
  #pragma unroll
  for (int jj = 0; jj < 6; ++jj) {
    int j = jj*64 + lane;
    size_t off = ((size_t)h*L_DIM + i)*L_DIM + j;
    float a = 0.f;
    #pragma unroll
    for (int ksp = 0; ksp < 8; ++ksp) a += Spart[(size_t)ksp*(NH*L_DIM*L_DIM) + off];
    a = a*sc + bscore[off];
    s[jj] = a; mx = fmaxf(mx, a);
  }
  #pragma unroll
  for (int off = 32; off; off >>= 1) mx = fmaxf(mx, __shfl_xor(mx, off, 64));
  float sum = 0.f;
  #pragma unroll
  for (int jj = 0; jj < 6; ++jj) { s[jj] = __expf(s[jj] - mx); sum += s[jj]; }
  #pragma unroll
  for (int off = 32; off; off >>= 1) sum += __shfl_xor(sum, off, 64);
  const float inv = 1.f / sum;
  #pragma unroll
  for (int jj = 0; jj < 6; ++jj) {
    int j = jj*64 + lane;
    attn[((size_t)h*L_DIM + i)*L_DIM + j] = f2bf(s[jj]*inv);
  }
}

// ---------------------------------------------------------------------------
// Kernel 4: out[n,i,h,d] = sum_j attn[h,i,j] * v[n,j,h,d]; gate fused; direct frag loads.
__global__ __launch_bounds__(256) void k_pv(
    const bf16* __restrict__ attn, const bf16* __restrict__ vT, const bf16* __restrict__ gate,
    bf16* __restrict__ gout)
{
  const int tid = threadIdx.x, wave = tid >> 6, lane = tid & 63;
  const int m = lane & 15, q4 = lane >> 4;
  const int n = blockIdx.x >> 2, h = blockIdx.x & 3;

  f4_t acc[6][2];
  #pragma unroll
  for (int a = 0; a < 6; ++a) { acc[a][0] = (f4_t){0,0,0,0}; acc[a][1] = (f4_t){0,0,0,0}; }

  const bf16* ap = attn + (size_t)h*L_DIM*L_DIM;
  const bf16* vp = vT + (size_t)(n*NH + h)*DHD*L_DIM;
  for (int kt = 0; kt < 12; ++kt) {
    const int jb = kt*32 + q4*8;
    bf8_t b0 = *(const bf8_t*)&vp[(size_t)m*L_DIM + jb];
    bf8_t b1 = *(const bf8_t*)&vp[(size_t)(16 + m)*L_DIM + jb];
    #pragma unroll
    for (int mt = 0; mt < 6; ++mt) {
      int i = wave*96 + mt*16 + m;
      bf8_t af = *(const bf8_t*)&ap[(size_t)i*L_DIM + jb];
      acc[mt][0] = __builtin_amdgcn_mfma_f32_16x16x32_bf16(af, b0, acc[mt][0], 0, 0, 0);
      acc[mt][1] = __builtin_amdgcn_mfma_f32_16x16x32_bf16(af, b1, acc[mt][1], 0, 0, 0);
    }
  }
  #pragma unroll
  for (int mt = 0; mt < 6; ++mt)
    #pragma unroll
    for (int dt = 0; dt < 2; ++dt)
      #pragma unroll
      for (int reg = 0; reg < 4; ++reg) {
        int i = wave*96 + mt*16 + q4*4 + reg;
        int d = dt*16 + m;
        size_t off = ((size_t)n*L_DIM + i)*HD + h*DHD + d;
        float g = bf2f(gate[off]);
        gout[off] = f2bf(g * acc[mt][dt][reg]);
      }
}

// ---------------------------------------------------------------------------
// Kernel 5: (gate*out) @ Wo.T + bo -> f32 output, stored transposed: result[i][n][:]
__global__ __launch_bounds__(256) void k_out(
    const bf16* __restrict__ gout, const bf16* __restrict__ Wo, const float* __restrict__ bo,
    float* __restrict__ outp)
{
  __shared__ __align__(16) float Cs[64][132];   // f32 tile; 132 even -> float2-safe
  const int tid = threadIdx.x, wave = tid >> 6, lane = tid & 63;
  const int m = lane & 15, q4 = lane >> 4;
  const int n = blockIdx.x / 6, i0 = (blockIdx.x % 6) * 64;

  bf8_t afr[4];
  const size_t rbase = ((size_t)n*L_DIM + i0 + wave*16 + m)*HD;
  #pragma unroll
  for (int ks = 0; ks < 4; ++ks) afr[ks] = *(const bf8_t*)&gout[rbase + ks*32 + q4*8];

  #pragma unroll
  for (int nt = 0; nt < 8; ++nt) {
    f4_t acc = {0.f, 0.f, 0.f, 0.f};
    #pragma unroll
    for (int ks = 0; ks < 4; ++ks) {
      bf8_t bfr = *(const bf8_t*)&Wo[(size_t)(nt*16 + m)*HD + ks*32 + q4*8];
      acc = __builtin_amdgcn_mfma_f32_16x16x32_bf16(afr[ks], bfr, acc, 0, 0, 0);
    }
    const int col = nt*16 + m;
    const float bov = bo[col];
    #pragma unroll
    for (int reg = 0; reg < 4; ++reg)
      Cs[wave*16 + q4*4 + reg][col] = acc[reg] + bov;
  }
  __syncthreads();
  for (int u = tid; u < 4096; u += 256) {
    int r = u >> 6, c2 = (u & 63) * 2;
    size_t off = ((size_t)(i0 + r)*L_DIM + n)*DPC + c2;   // transposed store
    *(float2*)&outp[off] = *(const float2*)&Cs[r][c2];
  }
}

// ---------------------------------------------------------------------------
extern "C" void kernel_launch(void* const* d_in, const int* in_sizes, int n_in,
                              void* d_out, int out_size, void* d_ws, size_t ws_size,
                              hipStream_t stream)
{
  (void)in_sizes; (void)n_in; (void)out_size; (void)ws_size;
  const float* pair = (const float*)d_in[0];
  const float* bias = (const float*)d_in[1];
  const float* lnpg = (const float*)d_in[2];
  const float* lnpb = (const float*)d_in[3];
  const float* lnbg = (const float*)d_in[4];
  const float* lnbb = (const float*)d_in[5];
  const float* Wq   = (const float*)d_in[6];
  const float* Wk   = (const float*)d_in[7];
  const float* Wv   = (const float*)d_in[8];
  const float* Wb   = (const float*)d_in[9];
  const float* Wg   = (const float*)d_in[10];
  const float* bg   = (const float*)d_in[11];
  const float* Wo   = (const float*)d_in[12];
  const float* bo   = (const float*)d_in[13];
  float* outp = (float*)d_out;

  char* ws = (char*)d_ws;
  const size_t SZ = (size_t)NROWS * HD * 2;            // 37.75 MB per bf16 tensor
  bf16* qo    = (bf16*)(ws);
  bf16* ko    = (bf16*)(ws + SZ);
  bf16* vT    = (bf16*)(ws + 2*SZ);
  bf16* gate  = (bf16*)(ws + 3*SZ);
  float* bscore = (float*)(ws + 4*SZ);
  float* Spart  = (float*)(ws + 4*SZ + (size_t)NH*L_DIM*L_DIM*4);
  bf16*  attn   = (bf16*)(ws + 4*SZ + (size_t)NH*L_DIM*L_DIM*4 + (size_t)8*NH*L_DIM*L_DIM*4);
  char*  wb     = ws + 4*SZ + (size_t)NH*L_DIM*L_DIM*4 + (size_t)8*NH*L_DIM*L_DIM*4
                     + (size_t)NH*L_DIM*L_DIM*2;
  bf16* Wqb = (bf16*)(wb);
  bf16* Wkb = (bf16*)(wb + 32768);
  bf16* Wvb = (bf16*)(wb + 65536);
  bf16* Wgb = (bf16*)(wb + 98304);
  bf16* Wob = (bf16*)(wb + 131072);
  bf16* gout = qo;   // q dead after k_qk

  hipLaunchKernelGGL(k_prep, dim3(64), dim3(256), 0, stream, Wq, Wk, Wv, Wg, Wo,
                     Wqb, Wkb, Wvb, Wgb, Wob);
  hipLaunchKernelGGL(k_bias_proj, dim3(NROWS/4), dim3(256), 0, stream, bias, lnbg, lnbb, Wb, bscore);
  hipLaunchKernelGGL(k_pair_proj, dim3(NROWS/64), dim3(256), 0, stream, pair, lnpg, lnpb,
                     Wqb, Wkb, Wvb, Wgb, bg, qo, ko, vT, gate);
  hipLaunchKernelGGL(k_qk, dim3(288), dim3(256), 0, stream, qo, ko, Spart);
  hipLaunchKernelGGL(k_softmax, dim3(384), dim3(256), 0, stream, Spart, bscore, attn);
  hipLaunchKernelGGL(k_pv, dim3(L_DIM*NH), dim3(256), 0, stream, attn, vT, gate, gout);
  hipLaunchKernelGGL(k_out, dim3(NROWS/64), dim3(256), 0, stream, gout, Wob, bo, outp);
}

// Round 3
// 624.136 us; speedup vs baseline: 1.0136x; 1.0136x over previous
//
#include <hip/hip_runtime.h>
#include <hip/hip_bf16.h>

#define L_DIM 384
#define DPC 128
#define NH 4
#define DHD 32
#define HD 128
#define NROWS (L_DIM*L_DIM)
#define NSPLIT 16

typedef __hip_bfloat16 bf16;
typedef __attribute__((ext_vector_type(8))) short bf8_t;   // 8 bf16 (4 VGPRs)
typedef __attribute__((ext_vector_type(4))) short bf4_t;   // 4 bf16 (2 VGPRs)
typedef __attribute__((ext_vector_type(4))) float f4_t;

__device__ __forceinline__ float bf2f(bf16 x){ return __bfloat162float(x); }
__device__ __forceinline__ bf16 f2bf(float x){ return __float2bfloat16(x); }

// ---------------------------------------------------------------------------
// Kernel 0: convert f32 weights to bf16 in workspace (5 matrices of 128x128).
__global__ __launch_bounds__(256) void k_prep(
    const float* __restrict__ Wq, const float* __restrict__ Wk, const float* __restrict__ Wv,
    const float* __restrict__ Wg, const float* __restrict__ Wo,
    bf16* __restrict__ Wqb, bf16* __restrict__ Wkb, bf16* __restrict__ Wvb,
    bf16* __restrict__ Wgb, bf16* __restrict__ Wob)
{
  const int idx = blockIdx.x * 256 + threadIdx.x;   // 64 blocks * 256 = 16384
  Wqb[idx] = f2bf(Wq[idx]);
  Wkb[idx] = f2bf(Wk[idx]);
  Wvb[idx] = f2bf(Wv[idx]);
  Wgb[idx] = f2bf(Wg[idx]);
  Wob[idx] = f2bf(Wo[idx]);
}

// ---------------------------------------------------------------------------
// Kernel 1b: LN(bias) + Wb -> bscore[h][i][j] (f32). 2 rows per wave, float4.
__global__ __launch_bounds__(256) void k_bias_proj(
    const float* __restrict__ bias, const float* __restrict__ lng, const float* __restrict__ lnb,
    const float* __restrict__ Wb, float* __restrict__ bscore)
{
  const int tid = threadIdx.x;
  const int wave = tid >> 6, lane = tid & 63;
  const int half = lane >> 5, l32 = lane & 31, c = l32 * 4;
  const int t = blockIdx.x * 8 + wave * 2 + half;    // memory row of bias
  const int j = t / L_DIM, i = t % L_DIM;            // bsrc[i][j] = bias row t

  const float4 g4 = *(const float4*)&lng[c];
  const float4 b4 = *(const float4*)&lnb[c];
  float4 w4[4];
  #pragma unroll
  for (int h = 0; h < 4; ++h) w4[h] = *(const float4*)&Wb[h*DPC + c];

  const float4 xv = *(const float4*)&bias[(size_t)t * DPC + c];
  float s  = xv.x + xv.y + xv.z + xv.w;
  float ss = xv.x*xv.x + xv.y*xv.y + xv.z*xv.z + xv.w*xv.w;
  #pragma unroll
  for (int off = 16; off; off >>= 1) { s += __shfl_xor(s, off, 64); ss += __shfl_xor(ss, off, 64); }
  const float mean = s * (1.f/128.f);
  const float var  = ss * (1.f/128.f) - mean*mean;
  const float rstd = rsqrtf(var + 1e-5f);
  const float y0 = (xv.x-mean)*rstd*g4.x + b4.x;
  const float y1 = (xv.y-mean)*rstd*g4.y + b4.y;
  const float y2 = (xv.z-mean)*rstd*g4.z + b4.z;
  const float y3 = (xv.w-mean)*rstd*g4.w + b4.w;

  float p[4];
  #pragma unroll
  for (int h = 0; h < 4; ++h) {
    p[h] = y0*w4[h].x + y1*w4[h].y + y2*w4[h].z + y3*w4[h].w;
    #pragma unroll
    for (int off = 16; off; off >>= 1) p[h] += __shfl_xor(p[h], off, 64);
  }
  if (l32 == 0) {
    #pragma unroll
    for (int h = 0; h < 4; ++h)
      bscore[((size_t)h*L_DIM + i)*L_DIM + j] = p[h];
  }
}

// ---------------------------------------------------------------------------
// Kernel 1: LN(pair, transposed read, f32) + Q/K/V/G projections via bf16 MFMA.
// Block: 64 rows (fixed n, 64 consecutive i), 256 threads (4 waves).
__global__ __launch_bounds__(256) void k_pair_proj(
    const float* __restrict__ pair, const float* __restrict__ lng, const float* __restrict__ lnb,
    const bf16* __restrict__ Wq, const bf16* __restrict__ Wk, const bf16* __restrict__ Wv,
    const bf16* __restrict__ Wg, const float* __restrict__ bg,
    bf16* __restrict__ qo, bf16* __restrict__ ko, bf16* __restrict__ vT, bf16* __restrict__ gateo)
{
  __shared__ __align__(16) bf16 As[64][136];     // 272B rows = 17*16B aligned
  __shared__ __align__(16) bf16 Cbuf[9216];      // Cs 64x136 (8704) or Ct 128x72 (9216)
  #define CS(r,cc) Cbuf[(r)*136 + (cc)]
  #define CT(cc,r) Cbuf[(cc)*72 + (r)]
  const int tid = threadIdx.x;
  const int wave = tid >> 6, lane = tid & 63;
  const int n = blockIdx.x / 6, i0 = (blockIdx.x % 6) * 64;
  const int m = lane & 15, q4 = lane >> 4;

  { // LayerNorm -> As (bf16): 2 rows in flight per wave, float4 loads, all prefetched
    const int half = lane >> 5, l32 = lane & 31, c = l32 * 4;
    const float4 g4 = *(const float4*)&lng[c];
    const float4 b4 = *(const float4*)&lnb[c];
    float4 xv[8];
    #pragma unroll
    for (int rr = 0; rr < 8; ++rr) {
      int r = wave*16 + rr*2 + half;
      xv[rr] = *(const float4*)&pair[((size_t)(i0 + r)*L_DIM + n)*DPC + c];
    }
    #pragma unroll
    for (int rr = 0; rr < 8; ++rr) {
      int r = wave*16 + rr*2 + half;
      float s  = xv[rr].x + xv[rr].y + xv[rr].z + xv[rr].w;
      float ss = xv[rr].x*xv[rr].x + xv[rr].y*xv[rr].y + xv[rr].z*xv[rr].z + xv[rr].w*xv[rr].w;
      #pragma unroll
      for (int off = 16; off; off >>= 1) { s += __shfl_xor(s, off, 64); ss += __shfl_xor(ss, off, 64); }
      float mean = s * (1.f/128.f);
      float var  = ss * (1.f/128.f) - mean*mean;
      float rstd = rsqrtf(var + 1e-5f);
      union { bf16 h[4]; bf4_t v; } pk;
      pk.h[0] = f2bf((xv[rr].x-mean)*rstd*g4.x + b4.x);
      pk.h[1] = f2bf((xv[rr].y-mean)*rstd*g4.y + b4.y);
      pk.h[2] = f2bf((xv[rr].z-mean)*rstd*g4.z + b4.z);
      pk.h[3] = f2bf((xv[rr].w-mean)*rstd*g4.w + b4.w);
      *(bf4_t*)&As[r][c] = pk.v;
    }
  }
  __syncthreads();

  bf8_t afr[4];
  #pragma unroll
  for (int ks = 0; ks < 4; ++ks)
    afr[ks] = *(const bf8_t*)&As[wave*16 + m][ks*32 + q4*8];

  const bf16* Ws[4] = {Wq, Wk, Wv, Wg};
  for (int sel = 0; sel < 4; ++sel) {
    const bf16* W = Ws[sel];
    #pragma unroll
    for (int nt = 0; nt < 8; ++nt) {
      f4_t acc = {0.f, 0.f, 0.f, 0.f};
      #pragma unroll
      for (int ks = 0; ks < 4; ++ks) {
        bf8_t bfr = *(const bf8_t*)&W[(size_t)(nt*16 + m)*DPC + ks*32 + q4*8];
        acc = __builtin_amdgcn_mfma_f32_16x16x32_bf16(afr[ks], bfr, acc, 0, 0, 0);
      }
      const int col = nt*16 + m;
      if (sel == 2) {          // V: write transposed tile (col-major)
        #pragma unroll
        for (int reg = 0; reg < 4; ++reg)
          CT(col, wave*16 + q4*4 + reg) = f2bf(acc[reg]);
      } else {
        const float bgv = (sel == 3) ? bg[col] : 0.f;
        #pragma unroll
        for (int reg = 0; reg < 4; ++reg) {
          float v = acc[reg];
          if (sel == 3) v = 1.f / (1.f + __expf(-(v + bgv)));   // gate sigmoid
          CS(wave*16 + q4*4 + reg, col) = f2bf(v);
        }
      }
    }
    __syncthreads();
    if (sel == 2) {
      // vT[((n*4+h)*32+d)*L + i], 16B stores along i
      for (int u = tid; u < 1024; u += 256) {
        int colv = u >> 3, ii8 = (u & 7) * 8;
        int h = colv >> 5, d = colv & 31;
        size_t dst = ((size_t)(n*NH + h)*DHD + d)*L_DIM + i0 + ii8;
        *(bf8_t*)&vT[dst] = *(const bf8_t*)&CT(colv, ii8);
      }
    } else {
      bf16* dst = (sel == 0) ? qo : (sel == 1) ? ko : gateo;
      for (int u = tid; u < 1024; u += 256) {
        int r = u >> 4, c8 = (u & 15) * 8;
        size_t off = ((size_t)n*L_DIM + i0 + r)*HD + c8;
        *(bf8_t*)&dst[off] = *(const bf8_t*)&CS(r, c8);
      }
    }
    __syncthreads();
  }
  #undef CS
  #undef CT
}

// ---------------------------------------------------------------------------
// Kernel 2: S partials. Barrier-free direct fragment loads; split-K=16 (24 n's each).
__global__ __launch_bounds__(256) void k_qk(
    const bf16* __restrict__ qo, const bf16* __restrict__ ko, float* __restrict__ Spart)
{
  const int tid = threadIdx.x, wave = tid >> 6, lane = tid & 63;
  const int m = lane & 15, q4 = lane >> 4;
  const int b = blockIdx.x;
  const int ks = b / 36, rem = b % 36;
  const int h = rem / 9, t9 = rem % 9;
  const int i0 = (t9/3)*128, j0 = (t9%3)*128;
  const int wr = (wave >> 1)*64, wc = (wave & 1)*64;

  f4_t acc[4][4];
  #pragma unroll
  for (int a = 0; a < 4; ++a)
    #pragma unroll
    for (int c = 0; c < 4; ++c) acc[a][c] = (f4_t){0.f,0.f,0.f,0.f};

  const size_t hoff = (size_t)h*DHD + q4*8;
  #pragma unroll 2
  for (int kt = 0; kt < 24; ++kt) {
    const int nIdx = ks*24 + kt;
    const bf16* qbase = qo + (size_t)nIdx*L_DIM*HD + hoff;
    const bf16* kbase = ko + (size_t)nIdx*L_DIM*HD + hoff;
    bf8_t af[4], bfr[4];
    #pragma unroll
    for (int x = 0; x < 4; ++x) {
      af[x]  = *(const bf8_t*)&qbase[(size_t)(i0 + wr + x*16 + m)*HD];
      bfr[x] = *(const bf8_t*)&kbase[(size_t)(j0 + wc + x*16 + m)*HD];
    }
    #pragma unroll
    for (int mt = 0; mt < 4; ++mt)
      #pragma unroll
      for (int nt = 0; nt < 4; ++nt)
        acc[mt][nt] = __builtin_amdgcn_mfma_f32_16x16x32_bf16(af[mt], bfr[nt], acc[mt][nt], 0, 0, 0);
  }
  float* Sp = Spart + (size_t)(ks*NH + h)*L_DIM*L_DIM;
  #pragma unroll
  for (int mt = 0; mt < 4; ++mt)
    #pragma unroll
    for (int nt = 0; nt < 4; ++nt)
      #pragma unroll
      for (int reg = 0; reg < 4; ++reg) {
        int i = i0 + wr + mt*16 + q4*4 + reg;
        int j = j0 + wc + nt*16 + m;
        Sp[(size_t)i*L_DIM + j] = acc[mt][nt][reg];
      }
}

// ---------------------------------------------------------------------------
// Kernel 3: reduce split-K partials, scale, add bias score, softmax over j -> bf16 attn
__global__ __launch_bounds__(256) void k_softmax(
    const float* __restrict__ Spart, const float* __restrict__ bscore, bf16* __restrict__ attn)
{
  const int tid = threadIdx.x, wave = tid >> 6, lane = tid & 63;
  const int row = blockIdx.x*4 + wave;           // (h,i)
  const int h = row / L_DIM, i = row % L_DIM;
  const float sc = 0.17677669529663687f / 384.f; // SCALING * (1/L)
  float s[6]; float mx = -1e30f;
  #pragma unroll
  for (int jj = 0; jj < 6; ++jj) {
    int j = jj*64 + lane;
    size_t off = ((size_t)h*L_DIM + i)*L_DIM + j;
    float a = 0.f;
    #pragma unroll
    for (int ksp = 0; ksp < NSPLIT; ++ksp) a += Spart[(size_t)ksp*(NH*L_DIM*L_DIM) + off];
    a = a*sc + bscore[off];
    s[jj] = a; mx = fmaxf(mx, a);
  }
  #pragma unroll
  for (int off = 32; off; off >>= 1) mx = fmaxf(mx, __shfl_xor(mx, off, 64));
  float sum = 0.f;
  #pragma unroll
  for (int jj = 0; jj < 6; ++jj) { s[jj] = __expf(s[jj] - mx); sum += s[jj]; }
  #pragma unroll
  for (int off = 32; off; off >>= 1) sum += __shfl_xor(sum, off, 64);
  const float inv = 1.f / sum;
  #pragma unroll
  for (int jj = 0; jj < 6; ++jj) {
    int j = jj*64 + lane;
    attn[((size_t)h*L_DIM + i)*L_DIM + j] = f2bf(s[jj]*inv);
  }
}

// ---------------------------------------------------------------------------
// Kernel 4: out[n,i,h,d] = sum_j attn[h,i,j] * v[n,j,h,d]; gate fused; direct frag loads.
__global__ __launch_bounds__(256) void k_pv(
    const bf16* __restrict__ attn, const bf16* __restrict__ vT, const bf16* __restrict__ gate,
    bf16* __restrict__ gout)
{
  const int tid = threadIdx.x, wave = tid >> 6, lane = tid & 63;
  const int m = lane & 15, q4 = lane >> 4;
  const int n = blockIdx.x >> 2, h = blockIdx.x & 3;

  f4_t acc[6][2];
  #pragma unroll
  for (int a = 0; a < 6; ++a) { acc[a][0] = (f4_t){0,0,0,0}; acc[a][1] = (f4_t){0,0,0,0}; }

  const bf16* ap = attn + (size_t)h*L_DIM*L_DIM;
  const bf16* vp = vT + (size_t)(n*NH + h)*DHD*L_DIM;
  for (int kt = 0; kt < 12; ++kt) {
    const int jb = kt*32 + q4*8;
    bf8_t b0 = *(const bf8_t*)&vp[(size_t)m*L_DIM + jb];
    bf8_t b1 = *(const bf8_t*)&vp[(size_t)(16 + m)*L_DIM + jb];
    #pragma unroll
    for (int mt = 0; mt < 6; ++mt) {
      int i = wave*96 + mt*16 + m;
      bf8_t af = *(const bf8_t*)&ap[(size_t)i*L_DIM + jb];
      acc[mt][0] = __builtin_amdgcn_mfma_f32_16x16x32_bf16(af, b0, acc[mt][0], 0, 0, 0);
      acc[mt][1] = __builtin_amdgcn_mfma_f32_16x16x32_bf16(af, b1, acc[mt][1], 0, 0, 0);
    }
  }
  #pragma unroll
  for (int mt = 0; mt < 6; ++mt)
    #pragma unroll
    for (int dt = 0; dt < 2; ++dt)
      #pragma unroll
      for (int reg = 0; reg < 4; ++reg) {
        int i = wave*96 + mt*16 + q4*4 + reg;
        int d = dt*16 + m;
        size_t off = ((size_t)n*L_DIM + i)*HD + h*DHD + d;
        float g = bf2f(gate[off]);
        gout[off] = f2bf(g * acc[mt][dt][reg]);
      }
}

// ---------------------------------------------------------------------------
// Kernel 5: (gate*out) @ Wo.T + bo -> f32 output, stored transposed: result[i][n][:]
__global__ __launch_bounds__(256) void k_out(
    const bf16* __restrict__ gout, const bf16* __restrict__ Wo, const float* __restrict__ bo,
    float* __restrict__ outp)
{
  __shared__ __align__(16) float Cs[64][132];   // 528B rows = 33*16B aligned
  const int tid = threadIdx.x, wave = tid >> 6, lane = tid & 63;
  const int m = lane & 15, q4 = lane >> 4;
  const int n = blockIdx.x / 6, i0 = (blockIdx.x % 6) * 64;

  bf8_t afr[4];
  const size_t rbase = ((size_t)n*L_DIM + i0 + wave*16 + m)*HD;
  #pragma unroll
  for (int ks = 0; ks < 4; ++ks) afr[ks] = *(const bf8_t*)&gout[rbase + ks*32 + q4*8];

  #pragma unroll
  for (int nt = 0; nt < 8; ++nt) {
    f4_t acc = {0.f, 0.f, 0.f, 0.f};
    #pragma unroll
    for (int ks = 0; ks < 4; ++ks) {
      bf8_t bfr = *(const bf8_t*)&Wo[(size_t)(nt*16 + m)*HD + ks*32 + q4*8];
      acc = __builtin_amdgcn_mfma_f32_16x16x32_bf16(afr[ks], bfr, acc, 0, 0, 0);
    }
    const int col = nt*16 + m;
    const float bov = bo[col];
    #pragma unroll
    for (int reg = 0; reg < 4; ++reg)
      Cs[wave*16 + q4*4 + reg][col] = acc[reg] + bov;
  }
  __syncthreads();
  for (int u = tid; u < 2048; u += 256) {
    int r = u >> 5, c4 = (u & 31) * 4;
    size_t off = ((size_t)(i0 + r)*L_DIM + n)*DPC + c4;   // transposed store
    *(float4*)&outp[off] = *(const float4*)&Cs[r][c4];
  }
}

// ---------------------------------------------------------------------------
extern "C" void kernel_launch(void* const* d_in, const int* in_sizes, int n_in,
                              void* d_out, int out_size, void* d_ws, size_t ws_size,
                              hipStream_t stream)
{
  (void)in_sizes; (void)n_in; (void)out_size; (void)ws_size;
  const float* pair = (const float*)d_in[0];
  const float* bias = (const float*)d_in[1];
  const float* lnpg = (const float*)d_in[2];
  const float* lnpb = (const float*)d_in[3];
  const float* lnbg = (const float*)d_in[4];
  const float* lnbb = (const float*)d_in[5];
  const float* Wq   = (const float*)d_in[6];
  const float* Wk   = (const float*)d_in[7];
  const float* Wv   = (const float*)d_in[8];
  const float* Wb   = (const float*)d_in[9];
  const float* Wg   = (const float*)d_in[10];
  const float* bg   = (const float*)d_in[11];
  const float* Wo   = (const float*)d_in[12];
  const float* bo   = (const float*)d_in[13];
  float* outp = (float*)d_out;

  char* ws = (char*)d_ws;
  const size_t SZ = (size_t)NROWS * HD * 2;            // 37.75 MB per bf16 tensor
  bf16* qo    = (bf16*)(ws);
  bf16* ko    = (bf16*)(ws + SZ);
  bf16* vT    = (bf16*)(ws + 2*SZ);
  bf16* gate  = (bf16*)(ws + 3*SZ);
  float* bscore = (float*)(ws + 4*SZ);
  float* Spart  = (float*)(ws + 4*SZ + (size_t)NH*L_DIM*L_DIM*4);
  bf16*  attn   = (bf16*)(ws + 4*SZ + (size_t)NH*L_DIM*L_DIM*4 + (size_t)NSPLIT*NH*L_DIM*L_DIM*4);
  char*  wb     = ws + 4*SZ + (size_t)NH*L_DIM*L_DIM*4 + (size_t)NSPLIT*NH*L_DIM*L_DIM*4
                     + (size_t)NH*L_DIM*L_DIM*2;
  bf16* Wqb = (bf16*)(wb);
  bf16* Wkb = (bf16*)(wb + 32768);
  bf16* Wvb = (bf16*)(wb + 65536);
  bf16* Wgb = (bf16*)(wb + 98304);
  bf16* Wob = (bf16*)(wb + 131072);
  bf16* gout = qo;   // q dead after k_qk

  hipLaunchKernelGGL(k_prep, dim3(64), dim3(256), 0, stream, Wq, Wk, Wv, Wg, Wo,
                     Wqb, Wkb, Wvb, Wgb, Wob);
  hipLaunchKernelGGL(k_bias_proj, dim3(NROWS/8), dim3(256), 0, stream, bias, lnbg, lnbb, Wb, bscore);
  hipLaunchKernelGGL(k_pair_proj, dim3(NROWS/64), dim3(256), 0, stream, pair, lnpg, lnpb,
                     Wqb, Wkb, Wvb, Wgb, bg, qo, ko, vT, gate);
  hipLaunchKernelGGL(k_qk, dim3(NSPLIT*36), dim3(256), 0, stream, qo, ko, Spart);
  hipLaunchKernelGGL(k_softmax, dim3(384), dim3(256), 0, stream, Spart, bscore, attn);
  hipLaunchKernelGGL(k_pv, dim3(L_DIM*NH), dim3(256), 0, stream, attn, vT, gate, gout);
  hipLaunchKernelGGL(k_out, dim3(NROWS/64), dim3(256), 0, stream, gout, Wob, bo, outp);
}

// Round 4
// 421.708 us; speedup vs baseline: 1.5001x; 1.4800x over previous
//
#include <hip/hip_runtime.h>
#include <hip/hip_bf16.h>

#define L_DIM 384
#define DPC 128
#define NH 4
#define DHD 32
#define HD 128
#define NROWS (L_DIM*L_DIM)
#define NSPLIT 16

typedef __hip_bfloat16 bf16;
typedef __attribute__((ext_vector_type(8))) short bf8_t;   // 8 bf16 (4 VGPRs)
typedef __attribute__((ext_vector_type(4))) short bf4_t;   // 4 bf16 (2 VGPRs)
typedef __attribute__((ext_vector_type(4))) float f4_t;

__device__ __forceinline__ float bf2f(bf16 x){ return __bfloat162float(x); }
__device__ __forceinline__ bf16 f2bf(float x){ return __float2bfloat16(x); }

union bfu8 { bf8_t v; bf16 h[8]; };

// ---------------------------------------------------------------------------
// Kernel 0: f32 weights -> fragment-major bf16 packs.
// Pack[o], o = ((nt*4+ks)*64 + lane)*8 + j  <=  W[nt*16+(lane&15)][ks*32+(lane>>4)*8+j]
// Consumer loads frag(nt,ks) = 16B at Pack + (nt*4+ks)*512 + lane*8  (coalesced 1KB/wave).
__global__ __launch_bounds__(256) void k_prep(
    const float* __restrict__ Wq, const float* __restrict__ Wk, const float* __restrict__ Wv,
    const float* __restrict__ Wg, const float* __restrict__ Wo,
    bf16* __restrict__ Wqp, bf16* __restrict__ Wkp, bf16* __restrict__ Wvp,
    bf16* __restrict__ Wgp, bf16* __restrict__ Wop)
{
  const int o = blockIdx.x * 256 + threadIdx.x;   // 64 blocks -> 16384
  const int j = o & 7, lane = (o >> 3) & 63, ks = (o >> 9) & 3, nt = o >> 11;
  const int src = (nt*16 + (lane & 15))*DPC + ks*32 + (lane >> 4)*8 + j;
  Wqp[o] = f2bf(Wq[src]);
  Wkp[o] = f2bf(Wk[src]);
  Wvp[o] = f2bf(Wv[src]);
  Wgp[o] = f2bf(Wg[src]);
  Wop[o] = f2bf(Wo[src]);
}

// ---------------------------------------------------------------------------
// Kernel 1b: LN(bias) + Wb -> bscore[h][i][j] (f32). 2 rows per wave, float4.
__global__ __launch_bounds__(256) void k_bias_proj(
    const float* __restrict__ bias, const float* __restrict__ lng, const float* __restrict__ lnb,
    const float* __restrict__ Wb, float* __restrict__ bscore)
{
  const int tid = threadIdx.x;
  const int wave = tid >> 6, lane = tid & 63;
  const int half = lane >> 5, l32 = lane & 31, c = l32 * 4;
  const int t = blockIdx.x * 8 + wave * 2 + half;    // memory row of bias
  const int j = t / L_DIM, i = t % L_DIM;            // bsrc[i][j] = bias row t

  const float4 g4 = *(const float4*)&lng[c];
  const float4 b4 = *(const float4*)&lnb[c];
  float4 w4[4];
  #pragma unroll
  for (int h = 0; h < 4; ++h) w4[h] = *(const float4*)&Wb[h*DPC + c];

  const float4 xv = *(const float4*)&bias[(size_t)t * DPC + c];
  float s  = xv.x + xv.y + xv.z + xv.w;
  float ss = xv.x*xv.x + xv.y*xv.y + xv.z*xv.z + xv.w*xv.w;
  #pragma unroll
  for (int off = 16; off; off >>= 1) { s += __shfl_xor(s, off, 64); ss += __shfl_xor(ss, off, 64); }
  const float mean = s * (1.f/128.f);
  const float var  = ss * (1.f/128.f) - mean*mean;
  const float rstd = rsqrtf(var + 1e-5f);
  const float y0 = (xv.x-mean)*rstd*g4.x + b4.x;
  const float y1 = (xv.y-mean)*rstd*g4.y + b4.y;
  const float y2 = (xv.z-mean)*rstd*g4.z + b4.z;
  const float y3 = (xv.w-mean)*rstd*g4.w + b4.w;

  float p[4];
  #pragma unroll
  for (int h = 0; h < 4; ++h) {
    p[h] = y0*w4[h].x + y1*w4[h].y + y2*w4[h].z + y3*w4[h].w;
    #pragma unroll
    for (int off = 16; off; off >>= 1) p[h] += __shfl_xor(p[h], off, 64);
  }
  if (l32 == 0) {
    #pragma unroll
    for (int h = 0; h < 4; ++h)
      bscore[((size_t)h*L_DIM + i)*L_DIM + j] = p[h];
  }
}

// ---------------------------------------------------------------------------
// Kernel 1: LN(pair^T) + Q/K/V/G projections. All outputs fragment-major:
//  qf/kf [((n*4+h)*24 + I)*512 + lane*8]   (A/B frag: row=16I+(ln&15), d=(ln>>4)*8+j)
//  gatef [((n*24 + I)*4 + h)*512 + lane*8] (A frag over c-chunks, c-chunk index = h)
//  vf    [(((n*4+h)*12 + J)*2 + dt)*512 + lane*8] (B frag: j=32J+(ln>>4)*8+jj, d=dt*16+(ln&15))
__global__ __launch_bounds__(256) void k_pair_proj(
    const float* __restrict__ pair, const float* __restrict__ lng, const float* __restrict__ lnb,
    const bf16* __restrict__ Wqp, const bf16* __restrict__ Wkp, const bf16* __restrict__ Wvp,
    const bf16* __restrict__ Wgp, const float* __restrict__ bg,
    bf16* __restrict__ qf, bf16* __restrict__ kf, bf16* __restrict__ vf, bf16* __restrict__ gatef)
{
  __shared__ __align__(16) bf16 As[64][136];     // 272B rows: 16B-aligned
  __shared__ __align__(16) bf16 Cbuf[10240];     // Cs 64x136 (8704) or CT 128x80 (10240)
  #define CS(r,cc) Cbuf[(r)*136 + (cc)]
  const int tid = threadIdx.x;
  const int wave = tid >> 6, lane = tid & 63;
  const int n = blockIdx.x / 6, i0 = (blockIdx.x % 6) * 64;
  const int m = lane & 15, q4 = lane >> 4;

  { // LayerNorm -> As (bf16): 2 rows in flight per wave, float4 loads, all prefetched
    const int half = lane >> 5, l32 = lane & 31, c = l32 * 4;
    const float4 g4 = *(const float4*)&lng[c];
    const float4 b4 = *(const float4*)&lnb[c];
    float4 xv[8];
    #pragma unroll
    for (int rr = 0; rr < 8; ++rr) {
      int r = wave*16 + rr*2 + half;
      xv[rr] = *(const float4*)&pair[((size_t)(i0 + r)*L_DIM + n)*DPC + c];
    }
    #pragma unroll
    for (int rr = 0; rr < 8; ++rr) {
      int r = wave*16 + rr*2 + half;
      float s  = xv[rr].x + xv[rr].y + xv[rr].z + xv[rr].w;
      float ss = xv[rr].x*xv[rr].x + xv[rr].y*xv[rr].y + xv[rr].z*xv[rr].z + xv[rr].w*xv[rr].w;
      #pragma unroll
      for (int off = 16; off; off >>= 1) { s += __shfl_xor(s, off, 64); ss += __shfl_xor(ss, off, 64); }
      float mean = s * (1.f/128.f);
      float var  = ss * (1.f/128.f) - mean*mean;
      float rstd = rsqrtf(var + 1e-5f);
      union { bf16 h[4]; bf4_t v; } pk;
      pk.h[0] = f2bf((xv[rr].x-mean)*rstd*g4.x + b4.x);
      pk.h[1] = f2bf((xv[rr].y-mean)*rstd*g4.y + b4.y);
      pk.h[2] = f2bf((xv[rr].z-mean)*rstd*g4.z + b4.z);
      pk.h[3] = f2bf((xv[rr].w-mean)*rstd*g4.w + b4.w);
      *(bf4_t*)&As[r][c] = pk.v;
    }
  }
  __syncthreads();

  bf8_t afr[4];
  #pragma unroll
  for (int ks = 0; ks < 4; ++ks)
    afr[ks] = *(const bf8_t*)&As[wave*16 + m][ks*32 + q4*8];

  const bf16* Ws[4] = {Wqp, Wkp, Wvp, Wgp};
  for (int sel = 0; sel < 4; ++sel) {
    const bf16* Wp = Ws[sel];
    #pragma unroll
    for (int nt = 0; nt < 8; ++nt) {
      f4_t acc = {0.f, 0.f, 0.f, 0.f};
      #pragma unroll
      for (int ks = 0; ks < 4; ++ks) {
        bf8_t bfr = *(const bf8_t*)&Wp[(nt*4 + ks)*512 + lane*8];   // coalesced, L1-hot
        acc = __builtin_amdgcn_mfma_f32_16x16x32_bf16(afr[ks], bfr, acc, 0, 0, 0);
      }
      const int col = nt*16 + m;
      if (sel == 2) {          // V: transposed tile CT[col][row], row-dim contiguous
        #pragma unroll
        for (int reg = 0; reg < 4; ++reg)
          Cbuf[col*80 + wave*16 + q4*4 + reg] = f2bf(acc[reg]);
      } else {
        const float bgv = (sel == 3) ? bg[col] : 0.f;
        #pragma unroll
        for (int reg = 0; reg < 4; ++reg) {
          float v = acc[reg];
          if (sel == 3) v = 1.f / (1.f + __expf(-(v + bgv)));   // gate sigmoid
          CS(wave*16 + q4*4 + reg, col) = f2bf(v);
        }
      }
    }
    __syncthreads();
    if (sel == 2) {
      for (int u = tid; u < 1024; u += 256) {
        int ln = u & 63, dt = (u >> 6) & 1, h = (u >> 7) & 3, Jl = u >> 9;
        bf8_t val = *(const bf8_t*)&Cbuf[(h*32 + dt*16 + (ln&15))*80 + Jl*32 + (ln>>4)*8];
        size_t dst = ((((size_t)n*NH + h)*12 + (i0>>5) + Jl)*2 + dt)*512 + (size_t)ln*8;
        *(bf8_t*)&vf[dst] = val;
      }
    } else {
      for (int u = tid; u < 1024; u += 256) {
        int Il = u >> 8, h = (u >> 6) & 3, ln = u & 63;
        bf8_t val = *(const bf8_t*)&CS(Il*16 + (ln&15), h*32 + (ln>>4)*8);
        if (sel == 3) {
          size_t dst = ((((size_t)n*24 + (i0>>4) + Il)*NH + h)*64 + ln)*8;
          *(bf8_t*)&gatef[dst] = val;
        } else {
          bf16* out = (sel == 0) ? qf : kf;
          size_t dst = ((((size_t)n*NH + h)*24 + (i0>>4) + Il)*64 + ln)*8;
          *(bf8_t*)&out[dst] = val;
        }
      }
    }
    __syncthreads();
  }
  #undef CS
}

// ---------------------------------------------------------------------------
// Kernel 2: S partials. Fragment-major coalesced loads; split-K=16 (24 n's each).
__global__ __launch_bounds__(256) void k_qk(
    const bf16* __restrict__ qf, const bf16* __restrict__ kf, float* __restrict__ Spart)
{
  const int tid = threadIdx.x, wave = tid >> 6, lane = tid & 63;
  const int m = lane & 15, q4 = lane >> 4;
  const int b = blockIdx.x;
  const int ks = b / 36, rem = b % 36;
  const int h = rem / 9, t9 = rem % 9;
  const int i0 = (t9/3)*128, j0 = (t9%3)*128;
  const int wr = (wave >> 1)*64, wc = (wave & 1)*64;

  f4_t acc[4][4];
  #pragma unroll
  for (int a = 0; a < 4; ++a)
    #pragma unroll
    for (int c = 0; c < 4; ++c) acc[a][c] = (f4_t){0.f,0.f,0.f,0.f};

  #pragma unroll 2
  for (int kt = 0; kt < 24; ++kt) {
    const int nIdx = ks*24 + kt;
    const bf16* qb = qf + (((size_t)nIdx*NH + h)*24 + ((i0 + wr) >> 4))*512;
    const bf16* kb = kf + (((size_t)nIdx*NH + h)*24 + ((j0 + wc) >> 4))*512;
    bf8_t af[4], bfr[4];
    #pragma unroll
    for (int x = 0; x < 4; ++x) {
      af[x]  = *(const bf8_t*)&qb[x*512 + lane*8];
      bfr[x] = *(const bf8_t*)&kb[x*512 + lane*8];
    }
    #pragma unroll
    for (int mt = 0; mt < 4; ++mt)
      #pragma unroll
      for (int nt = 0; nt < 4; ++nt)
        acc[mt][nt] = __builtin_amdgcn_mfma_f32_16x16x32_bf16(af[mt], bfr[nt], acc[mt][nt], 0, 0, 0);
  }
  float* Sp = Spart + (size_t)(ks*NH + h)*L_DIM*L_DIM;
  #pragma unroll
  for (int mt = 0; mt < 4; ++mt)
    #pragma unroll
    for (int nt = 0; nt < 4; ++nt)
      #pragma unroll
      for (int reg = 0; reg < 4; ++reg) {
        int i = i0 + wr + mt*16 + q4*4 + reg;
        int j = j0 + wc + nt*16 + m;
        Sp[(size_t)i*L_DIM + j] = acc[mt][nt][reg];
      }
}

// ---------------------------------------------------------------------------
// Kernel 3: reduce split-K, scale, +bias, softmax over j; write attn FRAG-MAJOR:
//  attnf[((h*24 + I)*12 + J)*512 + lane*8 + jj] = attn[h][16I+(ln&15)][32J+(ln>>4)*8+jj]
// Block = one (h,i) row, 192 threads, thread owns j=2t,2t+1.
__global__ __launch_bounds__(192) void k_softmax(
    const float* __restrict__ Spart, const float* __restrict__ bscore, bf16* __restrict__ attnf)
{
  const int t = threadIdx.x, wave = t >> 6, lane = t & 63;
  const int h = blockIdx.x / L_DIM, i = blockIdx.x % L_DIM;
  const float sc = 0.17677669529663687f / 384.f; // SCALING * (1/L)
  const size_t off = ((size_t)h*L_DIM + i)*L_DIM + t*2;

  float ax = 0.f, ay = 0.f;
  #pragma unroll
  for (int ksp = 0; ksp < NSPLIT; ++ksp) {
    float2 p = *(const float2*)&Spart[(size_t)ksp*(NH*L_DIM*L_DIM) + off];
    ax += p.x; ay += p.y;
  }
  const float2 bs = *(const float2*)&bscore[off];
  ax = ax*sc + bs.x;
  ay = ay*sc + bs.y;

  __shared__ float redm[3], reds[3];
  float mx = fmaxf(ax, ay);
  #pragma unroll
  for (int o = 32; o; o >>= 1) mx = fmaxf(mx, __shfl_xor(mx, o, 64));
  if (lane == 0) redm[wave] = mx;
  __syncthreads();
  mx = fmaxf(fmaxf(redm[0], redm[1]), redm[2]);
  float ex = __expf(ax - mx), ey = __expf(ay - mx);
  float sm = ex + ey;
  #pragma unroll
  for (int o = 32; o; o >>= 1) sm += __shfl_xor(sm, o, 64);
  if (lane == 0) reds[wave] = sm;
  __syncthreads();
  const float inv = 1.f / (reds[0] + reds[1] + reds[2]);

  const int j = t*2;
  const int I = i >> 4, mm = i & 15, J = j >> 5, q4 = (j >> 3) & 3, jj = j & 7;
  union { bf16 h2[2]; unsigned u; } pk;
  pk.h2[0] = f2bf(ex * inv);
  pk.h2[1] = f2bf(ey * inv);
  size_t a = ((((size_t)h*24 + I)*12 + J)*64 + q4*16 + mm)*8 + jj;
  *(unsigned*)&attnf[a] = pk.u;
}

// ---------------------------------------------------------------------------
// Kernel 4: PV + gate; all frag-major. Block per (n,h). Output goutf in A-frag
// layout for k_out: goutf[((n*24+I)*4 + h)*512 + lane*8].
__global__ __launch_bounds__(256) void k_pv(
    const bf16* __restrict__ attnf, const bf16* __restrict__ vf, const bf16* __restrict__ gatef,
    bf16* __restrict__ goutf)
{
  __shared__ __align__(16) bf16 Cs2[384*40];   // [i][d], pad 32->40 (80B rows, 16B-aligned)
  const int tid = threadIdx.x, wave = tid >> 6, lane = tid & 63;
  const int m = lane & 15, q4 = lane >> 4;
  const int n = blockIdx.x >> 2, h = blockIdx.x & 3;

  f4_t acc[6][2];
  #pragma unroll
  for (int a = 0; a < 6; ++a) { acc[a][0] = (f4_t){0,0,0,0}; acc[a][1] = (f4_t){0,0,0,0}; }

  for (int J = 0; J < 12; ++J) {
    const bf16* vb = vf + (((size_t)(n*NH + h)*12 + J)*2)*512;
    bf8_t b0 = *(const bf8_t*)&vb[lane*8];
    bf8_t b1 = *(const bf8_t*)&vb[512 + lane*8];
    #pragma unroll
    for (int mt = 0; mt < 6; ++mt) {
      const int I = wave*6 + mt;
      bf8_t af = *(const bf8_t*)&attnf[(((size_t)h*24 + I)*12 + J)*512 + (size_t)lane*8];
      acc[mt][0] = __builtin_amdgcn_mfma_f32_16x16x32_bf16(af, b0, acc[mt][0], 0, 0, 0);
      acc[mt][1] = __builtin_amdgcn_mfma_f32_16x16x32_bf16(af, b1, acc[mt][1], 0, 0, 0);
    }
  }
  // C-layout -> LDS [i][d]
  #pragma unroll
  for (int mt = 0; mt < 6; ++mt)
    #pragma unroll
    for (int dt = 0; dt < 2; ++dt)
      #pragma unroll
      for (int reg = 0; reg < 4; ++reg) {
        int i_loc = 16*(wave*6 + mt) + q4*4 + reg;
        Cs2[i_loc*40 + dt*16 + m] = f2bf(acc[mt][dt][reg]);
      }
  __syncthreads();
  // re-read as A-frags, apply gate, store coalesced
  #pragma unroll
  for (int it = 0; it < 6; ++it) {
    int u = tid + it*256;
    int I = u >> 6, ln = u & 63;
    bfu8 uc, ug, uo;
    uc.v = *(const bf8_t*)&Cs2[(I*16 + (ln&15))*40 + (ln>>4)*8];
    size_t gidx = ((((size_t)n*24 + I)*NH + h)*64 + ln)*8;
    ug.v = *(const bf8_t*)&gatef[gidx];
    #pragma unroll
    for (int e = 0; e < 8; ++e) uo.h[e] = f2bf(bf2f(uc.h[e]) * bf2f(ug.h[e]));
    *(bf8_t*)&goutf[gidx] = uo.v;
  }
}

// ---------------------------------------------------------------------------
// Kernel 5: goutf @ Wo.T + bo -> f32 output, stored transposed: result[i][n][:]
__global__ __launch_bounds__(256) void k_out(
    const bf16* __restrict__ goutf, const bf16* __restrict__ Wop, const float* __restrict__ bo,
    float* __restrict__ outp)
{
  __shared__ __align__(16) float Cs[64][132];
  const int tid = threadIdx.x, wave = tid >> 6, lane = tid & 63;
  const int m = lane & 15, q4 = lane >> 4;
  const int n = blockIdx.x / 6, i0 = (blockIdx.x % 6) * 64;

  bf8_t afr[4];
  #pragma unroll
  for (int ks = 0; ks < 4; ++ks)
    afr[ks] = *(const bf8_t*)&goutf[((((size_t)n*24 + (i0>>4) + wave)*NH + ks)*64 + lane)*8];

  #pragma unroll
  for (int nt = 0; nt < 8; ++nt) {
    f4_t acc = {0.f, 0.f, 0.f, 0.f};
    #pragma unroll
    for (int ks = 0; ks < 4; ++ks) {
      bf8_t bfr = *(const bf8_t*)&Wop[(nt*4 + ks)*512 + lane*8];
      acc = __builtin_amdgcn_mfma_f32_16x16x32_bf16(afr[ks], bfr, acc, 0, 0, 0);
    }
    const int col = nt*16 + m;
    const float bov = bo[col];
    #pragma unroll
    for (int reg = 0; reg < 4; ++reg)
      Cs[wave*16 + q4*4 + reg][col] = acc[reg] + bov;
  }
  __syncthreads();
  for (int u = tid; u < 2048; u += 256) {
    int r = u >> 5, c4 = (u & 31) * 4;
    size_t off = ((size_t)(i0 + r)*L_DIM + n)*DPC + c4;   // transposed store
    *(float4*)&outp[off] = *(const float4*)&Cs[r][c4];
  }
}

// ---------------------------------------------------------------------------
extern "C" void kernel_launch(void* const* d_in, const int* in_sizes, int n_in,
                              void* d_out, int out_size, void* d_ws, size_t ws_size,
                              hipStream_t stream)
{
  (void)in_sizes; (void)n_in; (void)out_size; (void)ws_size;
  const float* pair = (const float*)d_in[0];
  const float* bias = (const float*)d_in[1];
  const float* lnpg = (const float*)d_in[2];
  const float* lnpb = (const float*)d_in[3];
  const float* lnbg = (const float*)d_in[4];
  const float* lnbb = (const float*)d_in[5];
  const float* Wq   = (const float*)d_in[6];
  const float* Wk   = (const float*)d_in[7];
  const float* Wv   = (const float*)d_in[8];
  const float* Wb   = (const float*)d_in[9];
  const float* Wg   = (const float*)d_in[10];
  const float* bg   = (const float*)d_in[11];
  const float* Wo   = (const float*)d_in[12];
  const float* bo   = (const float*)d_in[13];
  float* outp = (float*)d_out;

  char* ws = (char*)d_ws;
  const size_t SZ = (size_t)NROWS * HD * 2;            // 37.75 MB per bf16 tensor
  bf16* qfb   = (bf16*)(ws);
  bf16* kfb   = (bf16*)(ws + SZ);
  bf16* vfb   = (bf16*)(ws + 2*SZ);
  bf16* gatef = (bf16*)(ws + 3*SZ);
  float* bscore = (float*)(ws + 4*SZ);
  float* Spart  = (float*)(ws + 4*SZ + (size_t)NH*L_DIM*L_DIM*4);
  bf16*  attnf  = (bf16*)(ws + 4*SZ + (size_t)NH*L_DIM*L_DIM*4 + (size_t)NSPLIT*NH*L_DIM*L_DIM*4);
  char*  wb     = ws + 4*SZ + (size_t)NH*L_DIM*L_DIM*4 + (size_t)NSPLIT*NH*L_DIM*L_DIM*4
                     + (size_t)NH*L_DIM*L_DIM*2;
  bf16* Wqp = (bf16*)(wb);
  bf16* Wkp = (bf16*)(wb + 32768);
  bf16* Wvp = (bf16*)(wb + 65536);
  bf16* Wgp = (bf16*)(wb + 98304);
  bf16* Wop = (bf16*)(wb + 131072);
  bf16* goutf = qfb;   // qf dead after k_qk

  hipLaunchKernelGGL(k_prep, dim3(64), dim3(256), 0, stream, Wq, Wk, Wv, Wg, Wo,
                     Wqp, Wkp, Wvp, Wgp, Wop);
  hipLaunchKernelGGL(k_bias_proj, dim3(NROWS/8), dim3(256), 0, stream, bias, lnbg, lnbb, Wb, bscore);
  hipLaunchKernelGGL(k_pair_proj, dim3(NROWS/64), dim3(256), 0, stream, pair, lnpg, lnpb,
                     Wqp, Wkp, Wvp, Wgp, bg, qfb, kfb, vfb, gatef);
  hipLaunchKernelGGL(k_qk, dim3(NSPLIT*36), dim3(256), 0, stream, qfb, kfb, Spart);
  hipLaunchKernelGGL(k_softmax, dim3(NH*L_DIM), dim3(192), 0, stream, Spart, bscore, attnf);
  hipLaunchKernelGGL(k_pv, dim3(L_DIM*NH), dim3(256), 0, stream, attnf, vfb, gatef, goutf);
  hipLaunchKernelGGL(k_out, dim3(NROWS/64), dim3(256), 0, stream, goutf, Wop, bo, outp);
}

// Round 5
// 396.777 us; speedup vs baseline: 1.5944x; 1.0628x over previous
//
#include <hip/hip_runtime.h>
#include <hip/hip_bf16.h>

#define L_DIM 384
#define DPC 128
#define NH 4
#define DHD 32
#define HD 128
#define NROWS (L_DIM*L_DIM)
#define NSPLIT 16

typedef __hip_bfloat16 bf16;
typedef __attribute__((ext_vector_type(8))) short bf8_t;   // 8 bf16 (4 VGPRs)
typedef __attribute__((ext_vector_type(4))) short bf4_t;   // 4 bf16 (2 VGPRs)
typedef __attribute__((ext_vector_type(4))) float f4_t;

__device__ __forceinline__ float bf2f(bf16 x){ return __bfloat162float(x); }
__device__ __forceinline__ bf16 f2bf(float x){ return __float2bfloat16(x); }

union bfu8 { bf8_t v; bf16 h[8]; };

// ---------------------------------------------------------------------------
// Kernel 0: f32 weights -> fragment-major bf16 packs.
// Pack[o], o = ((nt*4+ks)*64 + lane)*8 + j  <=  W[nt*16+(lane&15)][ks*32+(lane>>4)*8+j]
__global__ __launch_bounds__(256) void k_prep(
    const float* __restrict__ Wq, const float* __restrict__ Wk, const float* __restrict__ Wv,
    const float* __restrict__ Wg, const float* __restrict__ Wo,
    bf16* __restrict__ Wqp, bf16* __restrict__ Wkp, bf16* __restrict__ Wvp,
    bf16* __restrict__ Wgp, bf16* __restrict__ Wop)
{
  const int o = blockIdx.x * 256 + threadIdx.x;   // 64 blocks -> 16384
  const int j = o & 7, lane = (o >> 3) & 63, ks = (o >> 9) & 3, nt = o >> 11;
  const int src = (nt*16 + (lane & 15))*DPC + ks*32 + (lane >> 4)*8 + j;
  Wqp[o] = f2bf(Wq[src]);
  Wkp[o] = f2bf(Wk[src]);
  Wvp[o] = f2bf(Wv[src]);
  Wgp[o] = f2bf(Wg[src]);
  Wop[o] = f2bf(Wo[src]);
}

// ---------------------------------------------------------------------------
// Kernel 1b: LN(bias) + Wb -> bscore[h][i][j] (f32). 16 lanes/row, 4 rows/wave.
__global__ __launch_bounds__(256) void k_bias_proj(
    const float* __restrict__ bias, const float* __restrict__ lng, const float* __restrict__ lnb,
    const float* __restrict__ Wb, float* __restrict__ bscore)
{
  const int tid = threadIdx.x;
  const int wave = tid >> 6, lane = tid & 63;
  const int sub = lane >> 4, l16 = lane & 15, c = l16 * 8;
  const int t = blockIdx.x * 16 + wave * 4 + sub;    // memory row of bias
  const int j = t / L_DIM, i = t % L_DIM;            // bsrc[i][j] = bias row t

  const float4 ga = *(const float4*)&lng[c], gb = *(const float4*)&lng[c+4];
  const float4 ba = *(const float4*)&lnb[c], bb = *(const float4*)&lnb[c+4];
  const float4 xa = *(const float4*)&bias[(size_t)t * DPC + c];
  const float4 xb = *(const float4*)&bias[(size_t)t * DPC + c + 4];

  float s  = xa.x+xa.y+xa.z+xa.w + xb.x+xb.y+xb.z+xb.w;
  float ss = xa.x*xa.x+xa.y*xa.y+xa.z*xa.z+xa.w*xa.w
           + xb.x*xb.x+xb.y*xb.y+xb.z*xb.z+xb.w*xb.w;
  #pragma unroll
  for (int off = 8; off; off >>= 1) { s += __shfl_xor(s, off, 64); ss += __shfl_xor(ss, off, 64); }
  const float mean = s * (1.f/128.f);
  const float var  = ss * (1.f/128.f) - mean*mean;
  const float rstd = rsqrtf(var + 1e-5f);
  float y[8];
  y[0]=(xa.x-mean)*rstd*ga.x+ba.x; y[1]=(xa.y-mean)*rstd*ga.y+ba.y;
  y[2]=(xa.z-mean)*rstd*ga.z+ba.z; y[3]=(xa.w-mean)*rstd*ga.w+ba.w;
  y[4]=(xb.x-mean)*rstd*gb.x+bb.x; y[5]=(xb.y-mean)*rstd*gb.y+bb.y;
  y[6]=(xb.z-mean)*rstd*gb.z+bb.z; y[7]=(xb.w-mean)*rstd*gb.w+bb.w;

  float p[4];
  #pragma unroll
  for (int h = 0; h < 4; ++h) {
    const float4 wa = *(const float4*)&Wb[h*DPC + c];
    const float4 wb4 = *(const float4*)&Wb[h*DPC + c + 4];
    p[h] = y[0]*wa.x + y[1]*wa.y + y[2]*wa.z + y[3]*wa.w
         + y[4]*wb4.x + y[5]*wb4.y + y[6]*wb4.z + y[7]*wb4.w;
    #pragma unroll
    for (int off = 8; off; off >>= 1) p[h] += __shfl_xor(p[h], off, 64);
  }
  if (l16 == 0) {
    #pragma unroll
    for (int h = 0; h < 4; ++h)
      bscore[((size_t)h*L_DIM + i)*L_DIM + j] = p[h];
  }
}

// ---------------------------------------------------------------------------
// Kernel 1: LN(pair^T) + Q/K/V/G projections. 32 rows/block, 10 KB LDS union.
//  qf/kf [((n*4+h)*24 + I)*512 + lane*8]
//  gatef [((n*24 + I)*4 + h)*512 + lane*8]
//  vf    [(((n*4+h)*12 + J)*2 + dt)*512 + lane*8]
__global__ __launch_bounds__(256) void k_pair_proj(
    const float* __restrict__ pair, const float* __restrict__ lng, const float* __restrict__ lnb,
    const bf16* __restrict__ Wqp, const bf16* __restrict__ Wkp, const bf16* __restrict__ Wvp,
    const bf16* __restrict__ Wgp, const float* __restrict__ bg,
    bf16* __restrict__ qf, bf16* __restrict__ kf, bf16* __restrict__ vf, bf16* __restrict__ gatef)
{
  // Union buffer: As 32x136 (4352) | Cs 32x136 (4352) | CT 128x40 (5120)
  __shared__ __align__(16) bf16 Sh[5120];
  const int tid = threadIdx.x;
  const int wave = tid >> 6, lane = tid & 63;
  const int n = blockIdx.x / 12, i0 = (blockIdx.x % 12) * 32;
  const int m = lane & 15, q4 = lane >> 4;
  const int rt = wave >> 1, ch = wave & 1;   // row-tile (0/1), col-half (0/1)

  { // LayerNorm -> Sh (As): 8 rows per wave, 2 in flight (32 lanes each), float4
    const int half = lane >> 5, l32 = lane & 31, c = l32 * 4;
    const float4 g4 = *(const float4*)&lng[c];
    const float4 b4 = *(const float4*)&lnb[c];
    float4 xv[4];
    #pragma unroll
    for (int rr = 0; rr < 4; ++rr) {
      int r = wave*8 + rr*2 + half;
      xv[rr] = *(const float4*)&pair[((size_t)(i0 + r)*L_DIM + n)*DPC + c];
    }
    #pragma unroll
    for (int rr = 0; rr < 4; ++rr) {
      int r = wave*8 + rr*2 + half;
      float s  = xv[rr].x + xv[rr].y + xv[rr].z + xv[rr].w;
      float ss = xv[rr].x*xv[rr].x + xv[rr].y*xv[rr].y + xv[rr].z*xv[rr].z + xv[rr].w*xv[rr].w;
      #pragma unroll
      for (int off = 16; off; off >>= 1) { s += __shfl_xor(s, off, 64); ss += __shfl_xor(ss, off, 64); }
      float mean = s * (1.f/128.f);
      float var  = ss * (1.f/128.f) - mean*mean;
      float rstd = rsqrtf(var + 1e-5f);
      union { bf16 h[4]; bf4_t v; } pk;
      pk.h[0] = f2bf((xv[rr].x-mean)*rstd*g4.x + b4.x);
      pk.h[1] = f2bf((xv[rr].y-mean)*rstd*g4.y + b4.y);
      pk.h[2] = f2bf((xv[rr].z-mean)*rstd*g4.z + b4.z);
      pk.h[3] = f2bf((xv[rr].w-mean)*rstd*g4.w + b4.w);
      *(bf4_t*)&Sh[r*136 + c] = pk.v;
    }
  }
  __syncthreads();

  bf8_t afr[4];
  #pragma unroll
  for (int ks = 0; ks < 4; ++ks)
    afr[ks] = *(const bf8_t*)&Sh[(rt*16 + m)*136 + ks*32 + q4*8];
  __syncthreads();   // As now dead; Sh reused as C-tile

  const bf16* Ws[4] = {Wqp, Wkp, Wvp, Wgp};
  for (int sel = 0; sel < 4; ++sel) {
    const bf16* Wp = Ws[sel];
    #pragma unroll
    for (int ntl = 0; ntl < 4; ++ntl) {
      const int nt = ch*4 + ntl;
      f4_t acc = {0.f, 0.f, 0.f, 0.f};
      #pragma unroll
      for (int ks = 0; ks < 4; ++ks) {
        bf8_t bfr = *(const bf8_t*)&Wp[(nt*4 + ks)*512 + lane*8];   // coalesced, L1-hot
        acc = __builtin_amdgcn_mfma_f32_16x16x32_bf16(afr[ks], bfr, acc, 0, 0, 0);
      }
      const int col = nt*16 + m;
      if (sel == 2) {          // V: transposed tile CT[col][row]
        #pragma unroll
        for (int reg = 0; reg < 4; ++reg)
          Sh[col*40 + rt*16 + q4*4 + reg] = f2bf(acc[reg]);
      } else {
        const float bgv = (sel == 3) ? bg[col] : 0.f;
        #pragma unroll
        for (int reg = 0; reg < 4; ++reg) {
          float v = acc[reg];
          if (sel == 3) v = 1.f / (1.f + __expf(-(v + bgv)));   // gate sigmoid
          Sh[(rt*16 + q4*4 + reg)*136 + col] = f2bf(v);
        }
      }
    }
    __syncthreads();
    if (sel == 2) {
      for (int u = tid; u < 512; u += 256) {
        int ln = u & 63, dt = (u >> 6) & 1, h = u >> 7;
        bf8_t val = *(const bf8_t*)&Sh[(h*32 + dt*16 + (ln&15))*40 + (ln>>4)*8];
        size_t dst = ((((size_t)n*NH + h)*12 + (i0>>5))*2 + dt)*512 + (size_t)ln*8;
        *(bf8_t*)&vf[dst] = val;
      }
    } else {
      for (int u = tid; u < 512; u += 256) {
        int Il = u >> 8, h = (u >> 6) & 3, ln = u & 63;
        bf8_t val = *(const bf8_t*)&Sh[(Il*16 + (ln&15))*136 + h*32 + (ln>>4)*8];
        if (sel == 3) {
          size_t dst = ((((size_t)n*24 + (i0>>4) + Il)*NH + h)*64 + ln)*8;
          *(bf8_t*)&gatef[dst] = val;
        } else {
          bf16* out = (sel == 0) ? qf : kf;
          size_t dst = ((((size_t)n*NH + h)*24 + (i0>>4) + Il)*64 + ln)*8;
          *(bf8_t*)&out[dst] = val;
        }
      }
    }
    __syncthreads();
  }
}

// ---------------------------------------------------------------------------
// Kernel 2: S partials. Fragment-major coalesced loads; split-K=16 (24 n's each).
__global__ __launch_bounds__(256) void k_qk(
    const bf16* __restrict__ qf, const bf16* __restrict__ kf, float* __restrict__ Spart)
{
  const int tid = threadIdx.x, wave = tid >> 6, lane = tid & 63;
  const int m = lane & 15, q4 = lane >> 4;
  const int b = blockIdx.x;
  const int ks = b / 36, rem = b % 36;
  const int h = rem / 9, t9 = rem % 9;
  const int i0 = (t9/3)*128, j0 = (t9%3)*128;
  const int wr = (wave >> 1)*64, wc = (wave & 1)*64;

  f4_t acc[4][4];
  #pragma unroll
  for (int a = 0; a < 4; ++a)
    #pragma unroll
    for (int c = 0; c < 4; ++c) acc[a][c] = (f4_t){0.f,0.f,0.f,0.f};

  #pragma unroll 2
  for (int kt = 0; kt < 24; ++kt) {
    const int nIdx = ks*24 + kt;
    const bf16* qb = qf + (((size_t)nIdx*NH + h)*24 + ((i0 + wr) >> 4))*512;
    const bf16* kb = kf + (((size_t)nIdx*NH + h)*24 + ((j0 + wc) >> 4))*512;
    bf8_t af[4], bfr[4];
    #pragma unroll
    for (int x = 0; x < 4; ++x) {
      af[x]  = *(const bf8_t*)&qb[x*512 + lane*8];
      bfr[x] = *(const bf8_t*)&kb[x*512 + lane*8];
    }
    #pragma unroll
    for (int mt = 0; mt < 4; ++mt)
      #pragma unroll
      for (int nt = 0; nt < 4; ++nt)
        acc[mt][nt] = __builtin_amdgcn_mfma_f32_16x16x32_bf16(af[mt], bfr[nt], acc[mt][nt], 0, 0, 0);
  }
  float* Sp = Spart + (size_t)(ks*NH + h)*L_DIM*L_DIM;
  #pragma unroll
  for (int mt = 0; mt < 4; ++mt)
    #pragma unroll
    for (int nt = 0; nt < 4; ++nt)
      #pragma unroll
      for (int reg = 0; reg < 4; ++reg) {
        int i = i0 + wr + mt*16 + q4*4 + reg;
        int j = j0 + wc + nt*16 + m;
        Sp[(size_t)i*L_DIM + j] = acc[mt][nt][reg];
      }
}

// ---------------------------------------------------------------------------
// Kernel 3: reduce split-K, scale, +bias, softmax over j; write attn FRAG-MAJOR.
__global__ __launch_bounds__(192) void k_softmax(
    const float* __restrict__ Spart, const float* __restrict__ bscore, bf16* __restrict__ attnf)
{
  const int t = threadIdx.x, wave = t >> 6, lane = t & 63;
  const int h = blockIdx.x / L_DIM, i = blockIdx.x % L_DIM;
  const float sc = 0.17677669529663687f / 384.f; // SCALING * (1/L)
  const size_t off = ((size_t)h*L_DIM + i)*L_DIM + t*2;

  float ax = 0.f, ay = 0.f;
  #pragma unroll
  for (int ksp = 0; ksp < NSPLIT; ++ksp) {
    float2 p = *(const float2*)&Spart[(size_t)ksp*(NH*L_DIM*L_DIM) + off];
    ax += p.x; ay += p.y;
  }
  const float2 bs = *(const float2*)&bscore[off];
  ax = ax*sc + bs.x;
  ay = ay*sc + bs.y;

  __shared__ float redm[3], reds[3];
  float mx = fmaxf(ax, ay);
  #pragma unroll
  for (int o = 32; o; o >>= 1) mx = fmaxf(mx, __shfl_xor(mx, o, 64));
  if (lane == 0) redm[wave] = mx;
  __syncthreads();
  mx = fmaxf(fmaxf(redm[0], redm[1]), redm[2]);
  float ex = __expf(ax - mx), ey = __expf(ay - mx);
  float sm = ex + ey;
  #pragma unroll
  for (int o = 32; o; o >>= 1) sm += __shfl_xor(sm, o, 64);
  if (lane == 0) reds[wave] = sm;
  __syncthreads();
  const float inv = 1.f / (reds[0] + reds[1] + reds[2]);

  const int j = t*2;
  const int I = i >> 4, mm = i & 15, J = j >> 5, q4 = (j >> 3) & 3, jj = j & 7;
  union { bf16 h2[2]; unsigned u; } pk;
  pk.h2[0] = f2bf(ex * inv);
  pk.h2[1] = f2bf(ey * inv);
  size_t a = ((((size_t)h*24 + I)*12 + J)*64 + q4*16 + mm)*8 + jj;
  *(unsigned*)&attnf[a] = pk.u;
}

// ---------------------------------------------------------------------------
// Kernel 4: PV + gate; all frag-major. Block per (n,h).
__global__ __launch_bounds__(256) void k_pv(
    const bf16* __restrict__ attnf, const bf16* __restrict__ vf, const bf16* __restrict__ gatef,
    bf16* __restrict__ goutf)
{
  __shared__ __align__(16) bf16 Cs2[384*40];   // [i][d], pad 32->40
  const int tid = threadIdx.x, wave = tid >> 6, lane = tid & 63;
  const int m = lane & 15, q4 = lane >> 4;
  const int n = blockIdx.x >> 2, h = blockIdx.x & 3;

  f4_t acc[6][2];
  #pragma unroll
  for (int a = 0; a < 6; ++a) { acc[a][0] = (f4_t){0,0,0,0}; acc[a][1] = (f4_t){0,0,0,0}; }

  for (int J = 0; J < 12; ++J) {
    const bf16* vb = vf + (((size_t)(n*NH + h)*12 + J)*2)*512;
    bf8_t b0 = *(const bf8_t*)&vb[lane*8];
    bf8_t b1 = *(const bf8_t*)&vb[512 + lane*8];
    #pragma unroll
    for (int mt = 0; mt < 6; ++mt) {
      const int I = wave*6 + mt;
      bf8_t af = *(const bf8_t*)&attnf[(((size_t)h*24 + I)*12 + J)*512 + (size_t)lane*8];
      acc[mt][0] = __builtin_amdgcn_mfma_f32_16x16x32_bf16(af, b0, acc[mt][0], 0, 0, 0);
      acc[mt][1] = __builtin_amdgcn_mfma_f32_16x16x32_bf16(af, b1, acc[mt][1], 0, 0, 0);
    }
  }
  #pragma unroll
  for (int mt = 0; mt < 6; ++mt)
    #pragma unroll
    for (int dt = 0; dt < 2; ++dt)
      #pragma unroll
      for (int reg = 0; reg < 4; ++reg) {
        int i_loc = 16*(wave*6 + mt) + q4*4 + reg;
        Cs2[i_loc*40 + dt*16 + m] = f2bf(acc[mt][dt][reg]);
      }
  __syncthreads();
  #pragma unroll
  for (int it = 0; it < 6; ++it) {
    int u = tid + it*256;
    int I = u >> 6, ln = u & 63;
    bfu8 uc, ug, uo;
    uc.v = *(const bf8_t*)&Cs2[(I*16 + (ln&15))*40 + (ln>>4)*8];
    size_t gidx = ((((size_t)n*24 + I)*NH + h)*64 + ln)*8;
    ug.v = *(const bf8_t*)&gatef[gidx];
    #pragma unroll
    for (int e = 0; e < 8; ++e) uo.h[e] = f2bf(bf2f(uc.h[e]) * bf2f(ug.h[e]));
    *(bf8_t*)&goutf[gidx] = uo.v;
  }
}

// ---------------------------------------------------------------------------
// Kernel 5: goutf @ Wo.T + bo -> f32 output, stored transposed: result[i][n][:]
__global__ __launch_bounds__(256) void k_out(
    const bf16* __restrict__ goutf, const bf16* __restrict__ Wop, const float* __restrict__ bo,
    float* __restrict__ outp)
{
  __shared__ __align__(16) float Cs[64][132];
  const int tid = threadIdx.x, wave = tid >> 6, lane = tid & 63;
  const int m = lane & 15, q4 = lane >> 4;
  const int n = blockIdx.x / 6, i0 = (blockIdx.x % 6) * 64;

  bf8_t afr[4];
  #pragma unroll
  for (int ks = 0; ks < 4; ++ks)
    afr[ks] = *(const bf8_t*)&goutf[((((size_t)n*24 + (i0>>4) + wave)*NH + ks)*64 + lane)*8];

  #pragma unroll
  for (int nt = 0; nt < 8; ++nt) {
    f4_t acc = {0.f, 0.f, 0.f, 0.f};
    #pragma unroll
    for (int ks = 0; ks < 4; ++ks) {
      bf8_t bfr = *(const bf8_t*)&Wop[(nt*4 + ks)*512 + lane*8];
      acc = __builtin_amdgcn_mfma_f32_16x16x32_bf16(afr[ks], bfr, acc, 0, 0, 0);
    }
    const int col = nt*16 + m;
    const float bov = bo[col];
    #pragma unroll
    for (int reg = 0; reg < 4; ++reg)
      Cs[wave*16 + q4*4 + reg][col] = acc[reg] + bov;
  }
  __syncthreads();
  for (int u = tid; u < 2048; u += 256) {
    int r = u >> 5, c4 = (u & 31) * 4;
    size_t off = ((size_t)(i0 + r)*L_DIM + n)*DPC + c4;   // transposed store
    *(float4*)&outp[off] = *(const float4*)&Cs[r][c4];
  }
}

// ---------------------------------------------------------------------------
extern "C" void kernel_launch(void* const* d_in, const int* in_sizes, int n_in,
                              void* d_out, int out_size, void* d_ws, size_t ws_size,
                              hipStream_t stream)
{
  (void)in_sizes; (void)n_in; (void)out_size; (void)ws_size;
  const float* pair = (const float*)d_in[0];
  const float* bias = (const float*)d_in[1];
  const float* lnpg = (const float*)d_in[2];
  const float* lnpb = (const float*)d_in[3];
  const float* lnbg = (const float*)d_in[4];
  const float* lnbb = (const float*)d_in[5];
  const float* Wq   = (const float*)d_in[6];
  const float* Wk   = (const float*)d_in[7];
  const float* Wv   = (const float*)d_in[8];
  const float* Wb   = (const float*)d_in[9];
  const float* Wg   = (const float*)d_in[10];
  const float* bg   = (const float*)d_in[11];
  const float* Wo   = (const float*)d_in[12];
  const float* bo   = (const float*)d_in[13];
  float* outp = (float*)d_out;

  char* ws = (char*)d_ws;
  const size_t SZ = (size_t)NROWS * HD * 2;            // 37.75 MB per bf16 tensor
  bf16* qfb   = (bf16*)(ws);
  bf16* kfb   = (bf16*)(ws + SZ);
  bf16* vfb   = (bf16*)(ws + 2*SZ);
  bf16* gatef = (bf16*)(ws + 3*SZ);
  float* bscore = (float*)(ws + 4*SZ);
  float* Spart  = (float*)(ws + 4*SZ + (size_t)NH*L_DIM*L_DIM*4);
  bf16*  attnf  = (bf16*)(ws + 4*SZ + (size_t)NH*L_DIM*L_DIM*4 + (size_t)NSPLIT*NH*L_DIM*L_DIM*4);
  char*  wb     = ws + 4*SZ + (size_t)NH*L_DIM*L_DIM*4 + (size_t)NSPLIT*NH*L_DIM*L_DIM*4
                     + (size_t)NH*L_DIM*L_DIM*2;
  bf16* Wqp = (bf16*)(wb);
  bf16* Wkp = (bf16*)(wb + 32768);
  bf16* Wvp = (bf16*)(wb + 65536);
  bf16* Wgp = (bf16*)(wb + 98304);
  bf16* Wop = (bf16*)(wb + 131072);
  bf16* goutf = qfb;   // qf dead after k_qk

  hipLaunchKernelGGL(k_prep, dim3(64), dim3(256), 0, stream, Wq, Wk, Wv, Wg, Wo,
                     Wqp, Wkp, Wvp, Wgp, Wop);
  hipLaunchKernelGGL(k_bias_proj, dim3(NROWS/16), dim3(256), 0, stream, bias, lnbg, lnbb, Wb, bscore);
  hipLaunchKernelGGL(k_pair_proj, dim3(NROWS/32), dim3(256), 0, stream, pair, lnpg, lnpb,
                     Wqp, Wkp, Wvp, Wgp, bg, qfb, kfb, vfb, gatef);
  hipLaunchKernelGGL(k_qk, dim3(NSPLIT*36), dim3(256), 0, stream, qfb, kfb, Spart);
  hipLaunchKernelGGL(k_softmax, dim3(NH*L_DIM), dim3(192), 0, stream, Spart, bscore, attnf);
  hipLaunchKernelGGL(k_pv, dim3(L_DIM*NH), dim3(256), 0, stream, attnf, vfb, gatef, goutf);
  hipLaunchKernelGGL(k_out, dim3(NROWS/64), dim3(256), 0, stream, goutf, Wop, bo, outp);
}

// Round 6
// 389.151 us; speedup vs baseline: 1.6256x; 1.0196x over previous
//
#include <hip/hip_runtime.h>
#include <hip/hip_bf16.h>

#define L_DIM 384
#define DPC 128
#define NH 4
#define DHD 32
#define HD 128
#define NROWS (L_DIM*L_DIM)
#define NSPLIT 16

typedef __hip_bfloat16 bf16;
typedef __attribute__((ext_vector_type(8))) short bf8_t;   // 8 bf16 (4 VGPRs)
typedef __attribute__((ext_vector_type(4))) short bf4_t;   // 4 bf16 (2 VGPRs)
typedef __attribute__((ext_vector_type(4))) float f4_t;

__device__ __forceinline__ float bf2f(bf16 x){ return __bfloat162float(x); }
__device__ __forceinline__ bf16 f2bf(float x){ return __float2bfloat16(x); }

union bfu8 { bf8_t v; bf16 h[8]; };

// ---------------------------------------------------------------------------
// Kernel 0: f32 weights -> fragment-major bf16 packs.
__global__ __launch_bounds__(256) void k_prep(
    const float* __restrict__ Wq, const float* __restrict__ Wk, const float* __restrict__ Wv,
    const float* __restrict__ Wg, const float* __restrict__ Wo,
    bf16* __restrict__ Wqp, bf16* __restrict__ Wkp, bf16* __restrict__ Wvp,
    bf16* __restrict__ Wgp, bf16* __restrict__ Wop)
{
  const int o = blockIdx.x * 256 + threadIdx.x;   // 64 blocks -> 16384
  const int j = o & 7, lane = (o >> 3) & 63, ks = (o >> 9) & 3, nt = o >> 11;
  const int src = (nt*16 + (lane & 15))*DPC + ks*32 + (lane >> 4)*8 + j;
  Wqp[o] = f2bf(Wq[src]);
  Wkp[o] = f2bf(Wk[src]);
  Wvp[o] = f2bf(Wv[src]);
  Wgp[o] = f2bf(Wg[src]);
  Wop[o] = f2bf(Wo[src]);
}

// ---------------------------------------------------------------------------
// Kernel 1b: LN(bias) + Wb -> bscore[h][i][j] (f32). 16 lanes/row, 4 rows/wave.
__global__ __launch_bounds__(256) void k_bias_proj(
    const float* __restrict__ bias, const float* __restrict__ lng, const float* __restrict__ lnb,
    const float* __restrict__ Wb, float* __restrict__ bscore)
{
  const int tid = threadIdx.x;
  const int wave = tid >> 6, lane = tid & 63;
  const int sub = lane >> 4, l16 = lane & 15, c = l16 * 8;
  const int t = blockIdx.x * 16 + wave * 4 + sub;    // memory row of bias
  const int j = t / L_DIM, i = t % L_DIM;            // bsrc[i][j] = bias row t

  const float4 ga = *(const float4*)&lng[c], gb = *(const float4*)&lng[c+4];
  const float4 ba = *(const float4*)&lnb[c], bb = *(const float4*)&lnb[c+4];
  const float4 xa = *(const float4*)&bias[(size_t)t * DPC + c];
  const float4 xb = *(const float4*)&bias[(size_t)t * DPC + c + 4];

  float s  = xa.x+xa.y+xa.z+xa.w + xb.x+xb.y+xb.z+xb.w;
  float ss = xa.x*xa.x+xa.y*xa.y+xa.z*xa.z+xa.w*xa.w
           + xb.x*xb.x+xb.y*xb.y+xb.z*xb.z+xb.w*xb.w;
  #pragma unroll
  for (int off = 8; off; off >>= 1) { s += __shfl_xor(s, off, 64); ss += __shfl_xor(ss, off, 64); }
  const float mean = s * (1.f/128.f);
  const float var  = ss * (1.f/128.f) - mean*mean;
  const float rstd = rsqrtf(var + 1e-5f);
  float y[8];
  y[0]=(xa.x-mean)*rstd*ga.x+ba.x; y[1]=(xa.y-mean)*rstd*ga.y+ba.y;
  y[2]=(xa.z-mean)*rstd*ga.z+ba.z; y[3]=(xa.w-mean)*rstd*ga.w+ba.w;
  y[4]=(xb.x-mean)*rstd*gb.x+bb.x; y[5]=(xb.y-mean)*rstd*gb.y+bb.y;
  y[6]=(xb.z-mean)*rstd*gb.z+bb.z; y[7]=(xb.w-mean)*rstd*gb.w+bb.w;

  float p[4];
  #pragma unroll
  for (int h = 0; h < 4; ++h) {
    const float4 wa = *(const float4*)&Wb[h*DPC + c];
    const float4 wb4 = *(const float4*)&Wb[h*DPC + c + 4];
    p[h] = y[0]*wa.x + y[1]*wa.y + y[2]*wa.z + y[3]*wa.w
         + y[4]*wb4.x + y[5]*wb4.y + y[6]*wb4.z + y[7]*wb4.w;
    #pragma unroll
    for (int off = 8; off; off >>= 1) p[h] += __shfl_xor(p[h], off, 64);
  }
  if (l16 == 0) {
    #pragma unroll
    for (int h = 0; h < 4; ++h)
      bscore[((size_t)h*L_DIM + i)*L_DIM + j] = p[h];
  }
}

// ---------------------------------------------------------------------------
// Kernel 1: LN(pair^T) + Q/K/V/G projections. 32 rows/block.
// 3 barriers total; ALL global stores at kernel end (single implicit drain).
// LDS: AsCT union (5120) | Csq (4352) | Csk (4352) | Csg (4352) = 36.4 KB.
__global__ __launch_bounds__(256) void k_pair_proj(
    const float* __restrict__ pair, const float* __restrict__ lng, const float* __restrict__ lnb,
    const bf16* __restrict__ Wqp, const bf16* __restrict__ Wkp, const bf16* __restrict__ Wvp,
    const bf16* __restrict__ Wgp, const float* __restrict__ bg,
    bf16* __restrict__ qf, bf16* __restrict__ kf, bf16* __restrict__ vf, bf16* __restrict__ gatef)
{
  __shared__ __align__(16) bf16 Sh[5120 + 3*4352];
  bf16* AsCT = Sh;             // As: 32x136 (LN out) then reused as CT: 128x40 (v^T)
  bf16* Csq  = Sh + 5120;
  bf16* Csk  = Sh + 5120 + 4352;
  bf16* Csg  = Sh + 5120 + 2*4352;
  const int tid = threadIdx.x;
  const int wave = tid >> 6, lane = tid & 63;
  const int n = blockIdx.x / 12, i0 = (blockIdx.x % 12) * 32;
  const int m = lane & 15, q4 = lane >> 4;
  const int rt = wave >> 1, ch = wave & 1;   // row-tile (0/1), col-half (0/1)

  { // LayerNorm -> AsCT (pitch 136)
    const int half = lane >> 5, l32 = lane & 31, c = l32 * 4;
    const float4 g4 = *(const float4*)&lng[c];
    const float4 b4 = *(const float4*)&lnb[c];
    float4 xv[4];
    #pragma unroll
    for (int rr = 0; rr < 4; ++rr) {
      int r = wave*8 + rr*2 + half;
      xv[rr] = *(const float4*)&pair[((size_t)(i0 + r)*L_DIM + n)*DPC + c];
    }
    #pragma unroll
    for (int rr = 0; rr < 4; ++rr) {
      int r = wave*8 + rr*2 + half;
      float s  = xv[rr].x + xv[rr].y + xv[rr].z + xv[rr].w;
      float ss = xv[rr].x*xv[rr].x + xv[rr].y*xv[rr].y + xv[rr].z*xv[rr].z + xv[rr].w*xv[rr].w;
      #pragma unroll
      for (int off = 16; off; off >>= 1) { s += __shfl_xor(s, off, 64); ss += __shfl_xor(ss, off, 64); }
      float mean = s * (1.f/128.f);
      float var  = ss * (1.f/128.f) - mean*mean;
      float rstd = rsqrtf(var + 1e-5f);
      union { bf16 h[4]; bf4_t v; } pk;
      pk.h[0] = f2bf((xv[rr].x-mean)*rstd*g4.x + b4.x);
      pk.h[1] = f2bf((xv[rr].y-mean)*rstd*g4.y + b4.y);
      pk.h[2] = f2bf((xv[rr].z-mean)*rstd*g4.z + b4.z);
      pk.h[3] = f2bf((xv[rr].w-mean)*rstd*g4.w + b4.w);
      *(bf4_t*)&AsCT[r*136 + c] = pk.v;
    }
  }
  __syncthreads();   // B1: As complete

  bf8_t afr[4];
  #pragma unroll
  for (int ks = 0; ks < 4; ++ks)
    afr[ks] = *(const bf8_t*)&AsCT[(rt*16 + m)*136 + ks*32 + q4*8];

  // q, k, gate -> dedicated C-tiles (disjoint from As: no barrier needed)
  const bf16* W3[3] = {Wqp, Wkp, Wgp};
  bf16* C3[3] = {Csq, Csk, Csg};
  #pragma unroll
  for (int s3 = 0; s3 < 3; ++s3) {
    const bf16* Wp = W3[s3];
    bf16* Cs = C3[s3];
    #pragma unroll
    for (int ntl = 0; ntl < 4; ++ntl) {
      const int nt = ch*4 + ntl;
      f4_t acc = {0.f, 0.f, 0.f, 0.f};
      #pragma unroll
      for (int ks = 0; ks < 4; ++ks) {
        bf8_t bfr = *(const bf8_t*)&Wp[(nt*4 + ks)*512 + lane*8];   // L1-hot
        acc = __builtin_amdgcn_mfma_f32_16x16x32_bf16(afr[ks], bfr, acc, 0, 0, 0);
      }
      const int col = nt*16 + m;
      const float bgv = (s3 == 2) ? bg[col] : 0.f;
      #pragma unroll
      for (int reg = 0; reg < 4; ++reg) {
        float v = acc[reg];
        if (s3 == 2) v = 1.f / (1.f + __expf(-(v + bgv)));   // gate sigmoid
        Cs[(rt*16 + q4*4 + reg)*136 + col] = f2bf(v);
      }
    }
  }
  __syncthreads();   // B2: all afr reads done -> safe to overwrite As region with CT

  // v -> CT (As region, pitch 40)
  #pragma unroll
  for (int ntl = 0; ntl < 4; ++ntl) {
    const int nt = ch*4 + ntl;
    f4_t acc = {0.f, 0.f, 0.f, 0.f};
    #pragma unroll
    for (int ks = 0; ks < 4; ++ks) {
      bf8_t bfr = *(const bf8_t*)&Wvp[(nt*4 + ks)*512 + lane*8];
      acc = __builtin_amdgcn_mfma_f32_16x16x32_bf16(afr[ks], bfr, acc, 0, 0, 0);
    }
    const int col = nt*16 + m;
    #pragma unroll
    for (int reg = 0; reg < 4; ++reg)
      AsCT[col*40 + rt*16 + q4*4 + reg] = f2bf(acc[reg]);
  }
  __syncthreads();   // B3: all tiles complete

  // ---- all global stores, fire-and-forget, single drain at kernel end ----
  #pragma unroll
  for (int it = 0; it < 2; ++it) {
    int u = tid + it*256;
    { // v
      int ln = u & 63, dt = (u >> 6) & 1, h = u >> 7;
      bf8_t val = *(const bf8_t*)&AsCT[(h*32 + dt*16 + (ln&15))*40 + (ln>>4)*8];
      size_t dst = ((((size_t)n*NH + h)*12 + (i0>>5))*2 + dt)*512 + (size_t)ln*8;
      *(bf8_t*)&vf[dst] = val;
    }
    { // q, k, gate
      int Il = u >> 8, h = (u >> 6) & 3, ln = u & 63;
      int lidx = (Il*16 + (ln&15))*136 + h*32 + (ln>>4)*8;
      size_t dq = ((((size_t)n*NH + h)*24 + (i0>>4) + Il)*64 + ln)*8;
      *(bf8_t*)&qf[dq] = *(const bf8_t*)&Csq[lidx];
      *(bf8_t*)&kf[dq] = *(const bf8_t*)&Csk[lidx];
      size_t dg = ((((size_t)n*24 + (i0>>4) + Il)*NH + h)*64 + ln)*8;
      *(bf8_t*)&gatef[dg] = *(const bf8_t*)&Csg[lidx];
    }
  }
}

// ---------------------------------------------------------------------------
// Kernel 2: S partials. Frag-major loads + manual double-buffer prefetch.
__global__ __launch_bounds__(256) void k_qk(
    const bf16* __restrict__ qf, const bf16* __restrict__ kf, float* __restrict__ Spart)
{
  const int tid = threadIdx.x, wave = tid >> 6, lane = tid & 63;
  const int m = lane & 15, q4 = lane >> 4;
  const int b = blockIdx.x;
  const int ks = b / 36, rem = b % 36;
  const int h = rem / 9, t9 = rem % 9;
  const int i0 = (t9/3)*128, j0 = (t9%3)*128;
  const int wr = (wave >> 1)*64, wc = (wave & 1)*64;

  f4_t acc[4][4];
  #pragma unroll
  for (int a = 0; a < 4; ++a)
    #pragma unroll
    for (int c = 0; c < 4; ++c) acc[a][c] = (f4_t){0.f,0.f,0.f,0.f};

  const bf16* qp = qf + (((size_t)(ks*24)*NH + h)*24 + ((i0 + wr) >> 4))*512 + (size_t)lane*8;
  const bf16* kp = kf + (((size_t)(ks*24)*NH + h)*24 + ((j0 + wc) >> 4))*512 + (size_t)lane*8;
  const size_t nstride = (size_t)NH*24*512;   // one n step

  bf8_t af[4], bfr[4];
  #pragma unroll
  for (int x = 0; x < 4; ++x) {
    af[x]  = *(const bf8_t*)(qp + x*512);
    bfr[x] = *(const bf8_t*)(kp + x*512);
  }
  #pragma unroll 2
  for (int kt = 0; kt < 24; ++kt) {
    bf8_t afn[4], bfn[4];
    if (kt < 23) {
      const bf16* qn = qp + (size_t)(kt+1)*nstride;
      const bf16* kn = kp + (size_t)(kt+1)*nstride;
      #pragma unroll
      for (int x = 0; x < 4; ++x) {
        afn[x] = *(const bf8_t*)(qn + x*512);
        bfn[x] = *(const bf8_t*)(kn + x*512);
      }
    }
    #pragma unroll
    for (int mt = 0; mt < 4; ++mt)
      #pragma unroll
      for (int nt = 0; nt < 4; ++nt)
        acc[mt][nt] = __builtin_amdgcn_mfma_f32_16x16x32_bf16(af[mt], bfr[nt], acc[mt][nt], 0, 0, 0);
    #pragma unroll
    for (int x = 0; x < 4; ++x) { af[x] = afn[x]; bfr[x] = bfn[x]; }
  }
  float* Sp = Spart + (size_t)(ks*NH + h)*L_DIM*L_DIM;
  #pragma unroll
  for (int mt = 0; mt < 4; ++mt)
    #pragma unroll
    for (int nt = 0; nt < 4; ++nt)
      #pragma unroll
      for (int reg = 0; reg < 4; ++reg) {
        int i = i0 + wr + mt*16 + q4*4 + reg;
        int j = j0 + wc + nt*16 + m;
        Sp[(size_t)i*L_DIM + j] = acc[mt][nt][reg];
      }
}

// ---------------------------------------------------------------------------
// Kernel 3: reduce split-K, scale, +bias, softmax over j; write attn FRAG-MAJOR.
__global__ __launch_bounds__(192) void k_softmax(
    const float* __restrict__ Spart, const float* __restrict__ bscore, bf16* __restrict__ attnf)
{
  const int t = threadIdx.x, wave = t >> 6, lane = t & 63;
  const int h = blockIdx.x / L_DIM, i = blockIdx.x % L_DIM;
  const float sc = 0.17677669529663687f / 384.f; // SCALING * (1/L)
  const size_t off = ((size_t)h*L_DIM + i)*L_DIM + t*2;

  float ax = 0.f, ay = 0.f;
  #pragma unroll
  for (int ksp = 0; ksp < NSPLIT; ++ksp) {
    float2 p = *(const float2*)&Spart[(size_t)ksp*(NH*L_DIM*L_DIM) + off];
    ax += p.x; ay += p.y;
  }
  const float2 bs = *(const float2*)&bscore[off];
  ax = ax*sc + bs.x;
  ay = ay*sc + bs.y;

  __shared__ float redm[3], reds[3];
  float mx = fmaxf(ax, ay);
  #pragma unroll
  for (int o = 32; o; o >>= 1) mx = fmaxf(mx, __shfl_xor(mx, o, 64));
  if (lane == 0) redm[wave] = mx;
  __syncthreads();
  mx = fmaxf(fmaxf(redm[0], redm[1]), redm[2]);
  float ex = __expf(ax - mx), ey = __expf(ay - mx);
  float sm = ex + ey;
  #pragma unroll
  for (int o = 32; o; o >>= 1) sm += __shfl_xor(sm, o, 64);
  if (lane == 0) reds[wave] = sm;
  __syncthreads();
  const float inv = 1.f / (reds[0] + reds[1] + reds[2]);

  const int j = t*2;
  const int I = i >> 4, mm = i & 15, J = j >> 5, q4 = (j >> 3) & 3, jj = j & 7;
  union { bf16 h2[2]; unsigned u; } pk;
  pk.h2[0] = f2bf(ex * inv);
  pk.h2[1] = f2bf(ey * inv);
  size_t a = ((((size_t)h*24 + I)*12 + J)*64 + q4*16 + mm)*8 + jj;
  *(unsigned*)&attnf[a] = pk.u;
}

// ---------------------------------------------------------------------------
// Kernel 4: PV + gate; all frag-major. Block per (n,h). Gate loads hoisted.
__global__ __launch_bounds__(256) void k_pv(
    const bf16* __restrict__ attnf, const bf16* __restrict__ vf, const bf16* __restrict__ gatef,
    bf16* __restrict__ goutf)
{
  __shared__ __align__(16) bf16 Cs2[384*40];   // [i][d], pad 32->40
  const int tid = threadIdx.x, wave = tid >> 6, lane = tid & 63;
  const int m = lane & 15, q4 = lane >> 4;
  const int n = blockIdx.x >> 2, h = blockIdx.x & 3;

  // hoist HBM-cold gate fragments: overlap the whole MFMA loop
  bf8_t ugp[6];
  #pragma unroll
  for (int it = 0; it < 6; ++it) {
    int u = tid + it*256;
    int I = u >> 6, ln = u & 63;
    ugp[it] = *(const bf8_t*)&gatef[((((size_t)n*24 + I)*NH + h)*64 + ln)*8];
  }

  f4_t acc[6][2];
  #pragma unroll
  for (int a = 0; a < 6; ++a) { acc[a][0] = (f4_t){0,0,0,0}; acc[a][1] = (f4_t){0,0,0,0}; }

  for (int J = 0; J < 12; ++J) {
    const bf16* vb = vf + (((size_t)(n*NH + h)*12 + J)*2)*512;
    bf8_t b0 = *(const bf8_t*)&vb[lane*8];
    bf8_t b1 = *(const bf8_t*)&vb[512 + lane*8];
    #pragma unroll
    for (int mt = 0; mt < 6; ++mt) {
      const int I = wave*6 + mt;
      bf8_t af = *(const bf8_t*)&attnf[(((size_t)h*24 + I)*12 + J)*512 + (size_t)lane*8];
      acc[mt][0] = __builtin_amdgcn_mfma_f32_16x16x32_bf16(af, b0, acc[mt][0], 0, 0, 0);
      acc[mt][1] = __builtin_amdgcn_mfma_f32_16x16x32_bf16(af, b1, acc[mt][1], 0, 0, 0);
    }
  }
  #pragma unroll
  for (int mt = 0; mt < 6; ++mt)
    #pragma unroll
    for (int dt = 0; dt < 2; ++dt)
      #pragma unroll
      for (int reg = 0; reg < 4; ++reg) {
        int i_loc = 16*(wave*6 + mt) + q4*4 + reg;
        Cs2[i_loc*40 + dt*16 + m] = f2bf(acc[mt][dt][reg]);
      }
  __syncthreads();
  #pragma unroll
  for (int it = 0; it < 6; ++it) {
    int u = tid + it*256;
    int I = u >> 6, ln = u & 63;
    bfu8 uc, ug, uo;
    uc.v = *(const bf8_t*)&Cs2[(I*16 + (ln&15))*40 + (ln>>4)*8];
    ug.v = ugp[it];
    #pragma unroll
    for (int e = 0; e < 8; ++e) uo.h[e] = f2bf(bf2f(uc.h[e]) * bf2f(ug.h[e]));
    size_t gidx = ((((size_t)n*24 + I)*NH + h)*64 + ln)*8;
    *(bf8_t*)&goutf[gidx] = uo.v;
  }
}

// ---------------------------------------------------------------------------
// Kernel 5: goutf @ Wo.T + bo -> f32 output, stored transposed: result[i][n][:]
__global__ __launch_bounds__(256) void k_out(
    const bf16* __restrict__ goutf, const bf16* __restrict__ Wop, const float* __restrict__ bo,
    float* __restrict__ outp)
{
  __shared__ __align__(16) float Cs[64][132];
  const int tid = threadIdx.x, wave = tid >> 6, lane = tid & 63;
  const int m = lane & 15, q4 = lane >> 4;
  const int n = blockIdx.x / 6, i0 = (blockIdx.x % 6) * 64;

  bf8_t afr[4];
  #pragma unroll
  for (int ks = 0; ks < 4; ++ks)
    afr[ks] = *(const bf8_t*)&goutf[((((size_t)n*24 + (i0>>4) + wave)*NH + ks)*64 + lane)*8];

  #pragma unroll
  for (int nt = 0; nt < 8; ++nt) {
    f4_t acc = {0.f, 0.f, 0.f, 0.f};
    #pragma unroll
    for (int ks = 0; ks < 4; ++ks) {
      bf8_t bfr = *(const bf8_t*)&Wop[(nt*4 + ks)*512 + lane*8];
      acc = __builtin_amdgcn_mfma_f32_16x16x32_bf16(afr[ks], bfr, acc, 0, 0, 0);
    }
    const int col = nt*16 + m;
    const float bov = bo[col];
    #pragma unroll
    for (int reg = 0; reg < 4; ++reg)
      Cs[wave*16 + q4*4 + reg][col] = acc[reg] + bov;
  }
  __syncthreads();
  for (int u = tid; u < 2048; u += 256) {
    int r = u >> 5, c4 = (u & 31) * 4;
    size_t off = ((size_t)(i0 + r)*L_DIM + n)*DPC + c4;   // transposed store
    *(float4*)&outp[off] = *(const float4*)&Cs[r][c4];
  }
}

// ---------------------------------------------------------------------------
extern "C" void kernel_launch(void* const* d_in, const int* in_sizes, int n_in,
                              void* d_out, int out_size, void* d_ws, size_t ws_size,
                              hipStream_t stream)
{
  (void)in_sizes; (void)n_in; (void)out_size; (void)ws_size;
  const float* pair = (const float*)d_in[0];
  const float* bias = (const float*)d_in[1];
  const float* lnpg = (const float*)d_in[2];
  const float* lnpb = (const float*)d_in[3];
  const float* lnbg = (const float*)d_in[4];
  const float* lnbb = (const float*)d_in[5];
  const float* Wq   = (const float*)d_in[6];
  const float* Wk   = (const float*)d_in[7];
  const float* Wv   = (const float*)d_in[8];
  const float* Wb   = (const float*)d_in[9];
  const float* Wg   = (const float*)d_in[10];
  const float* bg   = (const float*)d_in[11];
  const float* Wo   = (const float*)d_in[12];
  const float* bo   = (const float*)d_in[13];
  float* outp = (float*)d_out;

  char* ws = (char*)d_ws;
  const size_t SZ = (size_t)NROWS * HD * 2;            // 37.75 MB per bf16 tensor
  bf16* qfb   = (bf16*)(ws);
  bf16* kfb   = (bf16*)(ws + SZ);
  bf16* vfb   = (bf16*)(ws + 2*SZ);
  bf16* gatef = (bf16*)(ws + 3*SZ);
  float* bscore = (float*)(ws + 4*SZ);
  float* Spart  = (float*)(ws + 4*SZ + (size_t)NH*L_DIM*L_DIM*4);
  bf16*  attnf  = (bf16*)(ws + 4*SZ + (size_t)NH*L_DIM*L_DIM*4 + (size_t)NSPLIT*NH*L_DIM*L_DIM*4);
  char*  wb     = ws + 4*SZ + (size_t)NH*L_DIM*L_DIM*4 + (size_t)NSPLIT*NH*L_DIM*L_DIM*4
                     + (size_t)NH*L_DIM*L_DIM*2;
  bf16* Wqp = (bf16*)(wb);
  bf16* Wkp = (bf16*)(wb + 32768);
  bf16* Wvp = (bf16*)(wb + 65536);
  bf16* Wgp = (bf16*)(wb + 98304);
  bf16* Wop = (bf16*)(wb + 131072);
  bf16* goutf = qfb;   // qf dead after k_qk

  hipLaunchKernelGGL(k_prep, dim3(64), dim3(256), 0, stream, Wq, Wk, Wv, Wg, Wo,
                     Wqp, Wkp, Wvp, Wgp, Wop);
  hipLaunchKernelGGL(k_bias_proj, dim3(NROWS/16), dim3(256), 0, stream, bias, lnbg, lnbb, Wb, bscore);
  hipLaunchKernelGGL(k_pair_proj, dim3(NROWS/32), dim3(256), 0, stream, pair, lnpg, lnpb,
                     Wqp, Wkp, Wvp, Wgp, bg, qfb, kfb, vfb, gatef);
  hipLaunchKernelGGL(k_qk, dim3(NSPLIT*36), dim3(256), 0, stream, qfb, kfb, Spart);
  hipLaunchKernelGGL(k_softmax, dim3(NH*L_DIM), dim3(192), 0, stream, Spart, bscore, attnf);
  hipLaunchKernelGGL(k_pv, dim3(L_DIM*NH), dim3(256), 0, stream, attnf, vfb, gatef, goutf);
  hipLaunchKernelGGL(k_out, dim3(NROWS/64), dim3(256), 0, stream, goutf, Wop, bo, outp);
}